// Round 1
// baseline (327.535 us; speedup 1.0000x reference)
//
#include <hip/hip_runtime.h>
#include <hip/hip_bf16.h>

// MHA forward, MI355X gfx950.
// Pipeline: cvt weights -> 3x proj GEMM (bf16 MFMA) -> causal flash attn -> out GEMM.
// HIDDEN=1024, HEADS=16, HEAD_DIM=64, B=2, S=2048.

typedef __attribute__((ext_vector_type(4))) float f32x4;
typedef __attribute__((ext_vector_type(8))) short bf16x8;  // 8 bf16 = 4 VGPRs (guide §3)

#define SEQ    2048
#define BATCH  2
#define NH     16
#define HD     64
#define HID    1024
#define MTOT   (BATCH * SEQ)   // 4096

static __device__ __forceinline__ unsigned short f2bf(float f) {
  union { float f; unsigned int u; } x; x.f = f;
  unsigned int r = x.u + 0x7fffu + ((x.u >> 16) & 1u);  // RNE
  return (unsigned short)(r >> 16);
}

// ---------------- weight f32 -> bf16 (4 matrices of 1M elems) ----------------
__global__ __launch_bounds__(256) void cvt4_kernel(
    const float* __restrict__ w0, const float* __restrict__ w1,
    const float* __restrict__ w2, const float* __restrict__ w3,
    unsigned short* __restrict__ dst) {
  const float* srcs[4] = {w0, w1, w2, w3};
  const float* s = srcs[blockIdx.y];
  unsigned short* d = dst + ((size_t)blockIdx.y << 20);
  int i = (blockIdx.x * 256 + threadIdx.x) * 4;
  float4 v = *(const float4*)(s + i);
  ushort4 o;
  o.x = f2bf(v.x); o.y = f2bf(v.y); o.z = f2bf(v.z); o.w = f2bf(v.w);
  *(ushort4*)(d + i) = o;
}

// ---------------- GEMM: C[M][1024] = X[M][1024] @ W[1024][1024]^T + bias -----
// MODE 0: X is f32, out bf16 scattered to [B,H,S,D]
// MODE 1: X is bf16, out f32 linear [M][1024]
// 128x128 tile, BK=32, 256 threads = 4 waves (2x2), each wave 64x64 (4x4 frags).
template <int MODE>
__global__ __launch_bounds__(256) void gemm_kernel(
    const void* __restrict__ Xin, const unsigned short* __restrict__ W,
    const float* __restrict__ bias, void* __restrict__ Out) {
  __shared__ unsigned short Xs[128][32];
  __shared__ unsigned short Ws[128][32];

  const int tid  = threadIdx.x;
  const int lane = tid & 63;
  const int wid  = tid >> 6;
  const int wm   = wid >> 1, wn = wid & 1;
  const int bm   = blockIdx.x * 128;
  const int bn   = blockIdx.y * 128;

  const int l15 = lane & 15;
  const int lhi = lane >> 4;        // 0..3

  f32x4 acc[4][4];
#pragma unroll
  for (int i = 0; i < 4; i++)
#pragma unroll
    for (int j = 0; j < 4; j++) acc[i][j] = (f32x4){0.f, 0.f, 0.f, 0.f};

  const int srow  = tid >> 1;        // 0..127
  const int skoff = (tid & 1) * 16;  // 0 or 16

  for (int k0 = 0; k0 < HID; k0 += 32) {
    // ---- stage X tile (128 rows x 32 k) ----
    {
      unsigned short* dst = &Xs[srow][skoff];
      if (MODE == 0) {
        const float* X = (const float*)Xin;
        const float* xp = X + (size_t)(bm + srow) * HID + k0 + skoff;
        float4 a0 = ((const float4*)xp)[0];
        float4 a1 = ((const float4*)xp)[1];
        float4 a2 = ((const float4*)xp)[2];
        float4 a3 = ((const float4*)xp)[3];
        ushort4 t0, t1, t2, t3;
        t0.x = f2bf(a0.x); t0.y = f2bf(a0.y); t0.z = f2bf(a0.z); t0.w = f2bf(a0.w);
        t1.x = f2bf(a1.x); t1.y = f2bf(a1.y); t1.z = f2bf(a1.z); t1.w = f2bf(a1.w);
        t2.x = f2bf(a2.x); t2.y = f2bf(a2.y); t2.z = f2bf(a2.z); t2.w = f2bf(a2.w);
        t3.x = f2bf(a3.x); t3.y = f2bf(a3.y); t3.z = f2bf(a3.z); t3.w = f2bf(a3.w);
        *(ushort4*)(dst + 0)  = t0;
        *(ushort4*)(dst + 4)  = t1;
        *(ushort4*)(dst + 8)  = t2;
        *(ushort4*)(dst + 12) = t3;
      } else {
        const unsigned short* X = (const unsigned short*)Xin;
        const unsigned short* xp = X + (size_t)(bm + srow) * HID + k0 + skoff;
        *(bf16x8*)(dst + 0) = *(const bf16x8*)(xp + 0);
        *(bf16x8*)(dst + 8) = *(const bf16x8*)(xp + 8);
      }
      // ---- stage W tile (128 n-rows x 32 k), W is [N][K] row-major bf16 ----
      const unsigned short* wp = W + (size_t)(bn + srow) * HID + k0 + skoff;
      unsigned short* wdst = &Ws[srow][skoff];
      *(bf16x8*)(wdst + 0) = *(const bf16x8*)(wp + 0);
      *(bf16x8*)(wdst + 8) = *(const bf16x8*)(wp + 8);
    }
    __syncthreads();

    bf16x8 af[4], bf[4];
#pragma unroll
    for (int i = 0; i < 4; i++) {
      af[i] = *(const bf16x8*)&Xs[wm * 64 + i * 16 + l15][lhi * 8];
      bf[i] = *(const bf16x8*)&Ws[wn * 64 + i * 16 + l15][lhi * 8];
    }
#pragma unroll
    for (int i = 0; i < 4; i++)
#pragma unroll
      for (int j = 0; j < 4; j++)
        acc[i][j] = __builtin_amdgcn_mfma_f32_16x16x32_bf16(af[i], bf[j], acc[i][j], 0, 0, 0);
    __syncthreads();
  }

  // ---- epilogue ----
  if (MODE == 0) {
    unsigned short* O = (unsigned short*)Out;
#pragma unroll
    for (int j = 0; j < 4; j++) {
      int n = bn + wn * 64 + j * 16 + l15;
      float bv = bias[n];
      int h = n >> 6, d = n & 63;
#pragma unroll
      for (int i = 0; i < 4; i++) {
#pragma unroll
        for (int r = 0; r < 4; r++) {
          int m = bm + wm * 64 + i * 16 + lhi * 4 + r;
          int b = m >> 11, s = m & 2047;
          O[(((size_t)(b * NH + h) * SEQ + s) << 6) + d] = f2bf(acc[i][j][r] + bv);
        }
      }
    }
  } else {
    float* O = (float*)Out;
#pragma unroll
    for (int j = 0; j < 4; j++) {
      int n = bn + wn * 64 + j * 16 + l15;
      float bv = bias[n];
#pragma unroll
      for (int i = 0; i < 4; i++) {
#pragma unroll
        for (int r = 0; r < 4; r++) {
          int m = bm + wm * 64 + i * 16 + lhi * 4 + r;
          O[(size_t)m * HID + n] = acc[i][j][r] + bv;
        }
      }
    }
  }
}

// ---------------- causal flash attention -------------------------------------
// Q,K,V: bf16 [B,H,S,D].  Out: bf16 [B,S,H*D].
// Block: one (b,h), one 64-row Q tile. 4 waves, wave w owns q rows w*16..+16.
__global__ __launch_bounds__(256) void attn_kernel(
    const unsigned short* __restrict__ Q, const unsigned short* __restrict__ K,
    const unsigned short* __restrict__ V, unsigned short* __restrict__ Aout) {
  __shared__ unsigned short Ks[64][64];
  __shared__ unsigned short Vt[64][64];      // transposed: Vt[d][s]
  __shared__ unsigned short Ps[4][16][64];   // per-wave P tile

  const int tid  = threadIdx.x;
  const int lane = tid & 63;
  const int w    = tid >> 6;
  const int l15  = lane & 15;
  const int lhi  = lane >> 4;

  const int qt = blockIdx.x;      // q tile 0..31
  const int bh = blockIdx.y;      // 0..31
  const int b  = bh >> 4, h = bh & 15;
  const size_t base = (size_t)bh * SEQ * HD;

  // Q fragments in registers (16 rows x 64 d per wave)
  const int qrow = qt * 64 + w * 16 + l15;
  bf16x8 aq[2];
  aq[0] = *(const bf16x8*)&Q[base + (size_t)qrow * HD + lhi * 8];
  aq[1] = *(const bf16x8*)&Q[base + (size_t)qrow * HD + 32 + lhi * 8];

  f32x4 o[4];
#pragma unroll
  for (int n = 0; n < 4; n++) o[n] = (f32x4){0.f, 0.f, 0.f, 0.f};
  float mold[4] = {-1e30f, -1e30f, -1e30f, -1e30f};
  float lrow[4] = {0.f, 0.f, 0.f, 0.f};

  const int srow = tid >> 2;        // 0..63
  const int sd   = (tid & 3) * 16;  // 0,16,32,48

  for (int kt = 0; kt <= qt; ++kt) {
    __syncthreads();  // previous tile's LDS reads done
    // ---- stage K and V^T tiles ----
    {
      const unsigned short* kp = K + base + (size_t)(kt * 64 + srow) * HD + sd;
      bf16x8 k0 = *(const bf16x8*)kp;
      bf16x8 k1 = *(const bf16x8*)(kp + 8);
      *(bf16x8*)&Ks[srow][sd]     = k0;
      *(bf16x8*)&Ks[srow][sd + 8] = k1;
      const unsigned short* vp = V + base + (size_t)(kt * 64 + srow) * HD + sd;
      bf16x8 v0 = *(const bf16x8*)vp;
      bf16x8 v1 = *(const bf16x8*)(vp + 8);
#pragma unroll
      for (int j = 0; j < 8; j++) Vt[sd + j][srow]     = (unsigned short)v0[j];
#pragma unroll
      for (int j = 0; j < 8; j++) Vt[sd + 8 + j][srow] = (unsigned short)v1[j];
    }
    __syncthreads();

    // ---- scores: S = Q K^T  (16 x 64 per wave) ----
    f32x4 sc[4];
#pragma unroll
    for (int n = 0; n < 4; n++) {
      sc[n] = (f32x4){0.f, 0.f, 0.f, 0.f};
#pragma unroll
      for (int ks = 0; ks < 2; ks++) {
        bf16x8 bk = *(const bf16x8*)&Ks[n * 16 + l15][ks * 32 + lhi * 8];
        sc[n] = __builtin_amdgcn_mfma_f32_16x16x32_bf16(aq[ks], bk, sc[n], 0, 0, 0);
      }
    }

    // ---- online softmax (rows = lhi*4 + r within wave's 16) ----
    const bool diag = (kt == qt);
    float fac[4];
    float p[4][4];  // [n][r]
#pragma unroll
    for (int r = 0; r < 4; r++) {
      int rowg = qt * 64 + w * 16 + lhi * 4 + r;
      float sv[4];
      float mx = -1e30f;
#pragma unroll
      for (int n = 0; n < 4; n++) {
        float v = sc[n][r] * 0.125f;  // 1/sqrt(64)
        int colg = kt * 64 + n * 16 + l15;
        if (diag && colg > rowg) v = -1e30f;
        sv[n] = v;
        mx = fmaxf(mx, v);
      }
#pragma unroll
      for (int msk = 1; msk < 16; msk <<= 1) mx = fmaxf(mx, __shfl_xor(mx, msk, 64));
      float mnew = fmaxf(mold[r], mx);
      float f = __expf(mold[r] - mnew);
      float ps = 0.f;
#pragma unroll
      for (int n = 0; n < 4; n++) {
        float e = __expf(sv[n] - mnew);
        p[n][r] = e;
        ps += e;
      }
#pragma unroll
      for (int msk = 1; msk < 16; msk <<= 1) ps += __shfl_xor(ps, msk, 64);
      lrow[r] = lrow[r] * f + ps;
      mold[r] = mnew;
      fac[r]  = f;
    }
#pragma unroll
    for (int n = 0; n < 4; n++) {
      o[n][0] *= fac[0]; o[n][1] *= fac[1]; o[n][2] *= fac[2]; o[n][3] *= fac[3];
    }

    // ---- P -> LDS (C-layout -> A-layout round trip) ----
#pragma unroll
    for (int n = 0; n < 4; n++)
#pragma unroll
      for (int r = 0; r < 4; r++)
        Ps[w][lhi * 4 + r][n * 16 + l15] = f2bf(p[n][r]);

    // ---- O += P V ----
    bf16x8 ap0 = *(const bf16x8*)&Ps[w][l15][lhi * 8];
    bf16x8 ap1 = *(const bf16x8*)&Ps[w][l15][32 + lhi * 8];
#pragma unroll
    for (int n = 0; n < 4; n++) {
      bf16x8 bv0 = *(const bf16x8*)&Vt[n * 16 + l15][lhi * 8];
      bf16x8 bv1 = *(const bf16x8*)&Vt[n * 16 + l15][32 + lhi * 8];
      o[n] = __builtin_amdgcn_mfma_f32_16x16x32_bf16(ap0, bv0, o[n], 0, 0, 0);
      o[n] = __builtin_amdgcn_mfma_f32_16x16x32_bf16(ap1, bv1, o[n], 0, 0, 0);
    }
  }

  // ---- normalize + write to [B,S,H*D] bf16 ----
#pragma unroll
  for (int n = 0; n < 4; n++) {
#pragma unroll
    for (int r = 0; r < 4; r++) {
      int rowg = qt * 64 + w * 16 + lhi * 4 + r;
      Aout[(((size_t)(b * SEQ + rowg)) << 10) + h * 64 + n * 16 + l15] =
          f2bf(o[n][r] / lrow[r]);
    }
  }
}

// ---------------- launch ------------------------------------------------------
extern "C" void kernel_launch(void* const* d_in, const int* in_sizes, int n_in,
                              void* d_out, int out_size, void* d_ws, size_t ws_size,
                              hipStream_t stream) {
  const float* q  = (const float*)d_in[0];
  const float* k  = (const float*)d_in[1];
  const float* v  = (const float*)d_in[2];
  const float* Wq = (const float*)d_in[3];
  const float* bq = (const float*)d_in[4];
  const float* Wk = (const float*)d_in[5];
  const float* bk = (const float*)d_in[6];
  const float* Wv = (const float*)d_in[7];
  const float* bv = (const float*)d_in[8];
  const float* Wo = (const float*)d_in[9];
  const float* bo = (const float*)d_in[10];
  float* out = (float*)d_out;

  unsigned short* ws  = (unsigned short*)d_ws;
  unsigned short* wqb = ws;                       // 1M elems each
  unsigned short* wkb = ws + (1u << 20);
  unsigned short* wvb = ws + (2u << 20);
  unsigned short* wob = ws + (3u << 20);
  unsigned short* Qb  = ws + (4u << 20);          // 4M elems each [B,H,S,D]
  unsigned short* Kb  = ws + (8u << 20);
  unsigned short* Vb  = ws + (12u << 20);
  unsigned short* Ab  = ws + (16u << 20);         // [B,S,H*D]

  cvt4_kernel<<<dim3(1024, 4), 256, 0, stream>>>(Wq, Wk, Wv, Wo, ws);

  gemm_kernel<0><<<dim3(32, 8), 256, 0, stream>>>((const void*)q, wqb, bq, (void*)Qb);
  gemm_kernel<0><<<dim3(32, 8), 256, 0, stream>>>((const void*)k, wkb, bk, (void*)Kb);
  gemm_kernel<0><<<dim3(32, 8), 256, 0, stream>>>((const void*)v, wvb, bv, (void*)Vb);

  attn_kernel<<<dim3(32, 32), 256, 0, stream>>>(Qb, Kb, Vb, Ab);

  gemm_kernel<1><<<dim3(32, 8), 256, 0, stream>>>((const void*)Ab, wob, bo, (void*)out);
}

// Round 2
// 233.239 us; speedup vs baseline: 1.4043x; 1.4043x over previous
//
#include <hip/hip_runtime.h>
#include <hip/hip_bf16.h>

// MHA forward, MI355X gfx950.
// cvt weights -> 3x proj GEMM (bf16 MFMA, V written pre-transposed) ->
// causal flash attn (2 k-groups, swizzled LDS) -> out GEMM.
// HIDDEN=1024, HEADS=16, HEAD_DIM=64, B=2, S=2048.

typedef __attribute__((ext_vector_type(4))) float f32x4;
typedef __attribute__((ext_vector_type(8))) short bf16x8;

#define SEQ    2048
#define BATCH  2
#define NH     16
#define HD     64
#define HID    1024

static __device__ __forceinline__ unsigned short f2bf(float f) {
  union { float f; unsigned int u; } x; x.f = f;
  unsigned int r = x.u + 0x7fffu + ((x.u >> 16) & 1u);  // RNE
  return (unsigned short)(r >> 16);
}

// XOR swizzle: col8 is an 8-elem-aligned bf16 column offset within a [*][64] row.
// Spreads the 16-lane same-column reads across banks (T2, §6 G4).
static __device__ __forceinline__ int swz(int row, int col8) {
  return col8 ^ ((row & 7) << 3);
}

// ---------------- weight f32 -> bf16 (4 matrices of 1M elems) ----------------
__global__ __launch_bounds__(256) void cvt4_kernel(
    const float* __restrict__ w0, const float* __restrict__ w1,
    const float* __restrict__ w2, const float* __restrict__ w3,
    unsigned short* __restrict__ dst) {
  const float* srcs[4] = {w0, w1, w2, w3};
  const float* s = srcs[blockIdx.y];
  unsigned short* d = dst + ((size_t)blockIdx.y << 20);
  int i = (blockIdx.x * 256 + threadIdx.x) * 4;
  float4 v = *(const float4*)(s + i);
  ushort4 o;
  o.x = f2bf(v.x); o.y = f2bf(v.y); o.z = f2bf(v.z); o.w = f2bf(v.w);
  *(ushort4*)(d + i) = o;
}

// ---------------- GEMM: C[M][1024] = X[M][1024] @ W[1024][1024]^T + bias -----
// MODE 0: X f32, out bf16 scattered [B,H,S,D]
// MODE 1: X bf16, out f32 linear [M][1024]
// MODE 2: X f32, out bf16 scattered TRANSPOSED [B,H,D,S]  (for V)
// 128x64 tile, BK=32, 256 threads = 4 waves (2x2), wave tile 64x32 (4x2 frags).
template <int MODE>
__global__ __launch_bounds__(256) void gemm_kernel(
    const void* __restrict__ Xin, const unsigned short* __restrict__ W,
    const float* __restrict__ bias, void* __restrict__ Out) {
  __shared__ unsigned short Xs[128][32];
  __shared__ unsigned short Wt[64][32];

  const int tid  = threadIdx.x;
  const int lane = tid & 63;
  const int wid  = tid >> 6;
  const int wm   = wid >> 1, wn = wid & 1;
  const int bm   = blockIdx.x * 128;
  const int bn   = blockIdx.y * 64;

  const int l15 = lane & 15;
  const int lhi = lane >> 4;

  f32x4 acc[4][2];
#pragma unroll
  for (int i = 0; i < 4; i++)
#pragma unroll
    for (int j = 0; j < 2; j++) acc[i][j] = (f32x4){0.f, 0.f, 0.f, 0.f};

  const int srow  = tid >> 1;        // 0..127
  const int skoff = (tid & 1) * 16;
  const int wrow  = tid >> 2;        // 0..63
  const int wkoff = (tid & 3) * 8;

  for (int k0 = 0; k0 < HID; k0 += 32) {
    {
      unsigned short* dst = &Xs[srow][skoff];
      if (MODE == 0 || MODE == 2) {
        const float* X = (const float*)Xin;
        const float* xp = X + (size_t)(bm + srow) * HID + k0 + skoff;
        float4 a0 = ((const float4*)xp)[0];
        float4 a1 = ((const float4*)xp)[1];
        float4 a2 = ((const float4*)xp)[2];
        float4 a3 = ((const float4*)xp)[3];
        ushort4 t0, t1, t2, t3;
        t0.x = f2bf(a0.x); t0.y = f2bf(a0.y); t0.z = f2bf(a0.z); t0.w = f2bf(a0.w);
        t1.x = f2bf(a1.x); t1.y = f2bf(a1.y); t1.z = f2bf(a1.z); t1.w = f2bf(a1.w);
        t2.x = f2bf(a2.x); t2.y = f2bf(a2.y); t2.z = f2bf(a2.z); t2.w = f2bf(a2.w);
        t3.x = f2bf(a3.x); t3.y = f2bf(a3.y); t3.z = f2bf(a3.z); t3.w = f2bf(a3.w);
        *(ushort4*)(dst + 0)  = t0;
        *(ushort4*)(dst + 4)  = t1;
        *(ushort4*)(dst + 8)  = t2;
        *(ushort4*)(dst + 12) = t3;
      } else {
        const unsigned short* X = (const unsigned short*)Xin;
        const unsigned short* xp = X + (size_t)(bm + srow) * HID + k0 + skoff;
        *(bf16x8*)(dst + 0) = *(const bf16x8*)(xp + 0);
        *(bf16x8*)(dst + 8) = *(const bf16x8*)(xp + 8);
      }
      const unsigned short* wp = W + (size_t)(bn + wrow) * HID + k0 + wkoff;
      *(bf16x8*)&Wt[wrow][wkoff] = *(const bf16x8*)wp;
    }
    __syncthreads();

    bf16x8 af[4], bfr[2];
#pragma unroll
    for (int i = 0; i < 4; i++)
      af[i] = *(const bf16x8*)&Xs[wm * 64 + i * 16 + l15][lhi * 8];
#pragma unroll
    for (int j = 0; j < 2; j++)
      bfr[j] = *(const bf16x8*)&Wt[wn * 32 + j * 16 + l15][lhi * 8];
#pragma unroll
    for (int i = 0; i < 4; i++)
#pragma unroll
      for (int j = 0; j < 2; j++)
        acc[i][j] = __builtin_amdgcn_mfma_f32_16x16x32_bf16(af[i], bfr[j], acc[i][j], 0, 0, 0);
    __syncthreads();
  }

  // ---- epilogue ----
#pragma unroll
  for (int j = 0; j < 2; j++) {
    int n = bn + wn * 32 + j * 16 + l15;
    float bv = bias[n];
    if (MODE == 1) {
      float* O = (float*)Out;
#pragma unroll
      for (int i = 0; i < 4; i++)
#pragma unroll
        for (int r = 0; r < 4; r++) {
          int m = bm + wm * 64 + i * 16 + lhi * 4 + r;
          O[(size_t)m * HID + n] = acc[i][j][r] + bv;
        }
    } else {
      unsigned short* O = (unsigned short*)Out;
      int h = n >> 6, d = n & 63;
#pragma unroll
      for (int i = 0; i < 4; i++)
#pragma unroll
        for (int r = 0; r < 4; r++) {
          int m = bm + wm * 64 + i * 16 + lhi * 4 + r;
          int b = m >> 11, s = m & 2047;
          if (MODE == 0)
            O[(((size_t)(b * NH + h) * SEQ + s) << 6) + d] = f2bf(acc[i][j][r] + bv);
          else  // MODE 2: V transposed [B,H,D,S]
            O[((size_t)(b * NH + h) * HD + d) * SEQ + s] = f2bf(acc[i][j][r] + bv);
        }
    }
  }
}

// ---------------- causal flash attention -------------------------------------
// Q,K: bf16 [B,H,S,D].  Vt: bf16 [B,H,D,S].  Out: bf16 [B,S,H*D].
// Block = (qt, bh): 512 thr = 8 waves = 2 k-groups x 4 row-waves.
// Group g processes kt = g, g+2, ...; partials merged at the end (flash-decoding).
__global__ __launch_bounds__(512) void attn_kernel(
    const unsigned short* __restrict__ Q, const unsigned short* __restrict__ K,
    const unsigned short* __restrict__ Vt, unsigned short* __restrict__ Aout) {
  // pool carve: Ksh[g] @ g*8192, Vsh[g] @ 16384+g*8192 ([64][64] swizzled),
  //             Psh[w] @ 32768+w*2304 ([16][72] padded). total 51200 B.
  __shared__ __align__(16) char pool[51200];

  const int tid  = threadIdx.x;
  const int lane = tid & 63;
  const int wid  = tid >> 6;
  const int rw   = wid & 3;       // row-wave 0..3
  const int g    = wid >> 2;      // k-group 0..1
  const int l15  = lane & 15;
  const int lhi  = lane >> 4;

  const int qt = blockIdx.x;
  const int bh = blockIdx.y;
  const int b  = bh >> 4, h = bh & 15;
  const size_t base = (size_t)bh * SEQ * HD;

  unsigned short* Ksh = (unsigned short*)(pool + g * 8192);
  unsigned short* Vsh = (unsigned short*)(pool + 16384 + g * 8192);
  unsigned short* Psh = (unsigned short*)(pool + 32768 + wid * 2304);

  // Q fragments (16 q-rows x 64 d per wave)
  const int qrow = qt * 64 + rw * 16 + l15;
  bf16x8 aq[2];
  aq[0] = *(const bf16x8*)&Q[base + (size_t)qrow * HD + lhi * 8];
  aq[1] = *(const bf16x8*)&Q[base + (size_t)qrow * HD + 32 + lhi * 8];

  f32x4 o[4];
#pragma unroll
  for (int n = 0; n < 4; n++) o[n] = (f32x4){0.f, 0.f, 0.f, 0.f};
  float mold[4] = {-1e30f, -1e30f, -1e30f, -1e30f};
  float lrow[4] = {0.f, 0.f, 0.f, 0.f};

  const int gt   = tid & 255;       // thread id within group
  const int srow = gt >> 2;         // 0..63
  const int sd   = (gt & 3) * 16;

  const int nsteps = qt / 2 + 1;
  for (int it = 0; it < nsteps; ++it) {
    const int kt = 2 * it + g;
    const bool act = (kt <= qt);
    __syncthreads();  // prior LDS reads done before overwrite
    if (act) {
      // K tile rows (s-major), swizzled
      const unsigned short* kp = K + base + (size_t)(kt * 64 + srow) * HD + sd;
      *(bf16x8*)&Ksh[srow * 64 + swz(srow, sd)]     = *(const bf16x8*)kp;
      *(bf16x8*)&Ksh[srow * 64 + swz(srow, sd + 8)] = *(const bf16x8*)(kp + 8);
      // V^T tile rows (d-major), from pre-transposed global, swizzled
      const unsigned short* vp = Vt + base + (size_t)srow * SEQ + kt * 64 + sd;
      *(bf16x8*)&Vsh[srow * 64 + swz(srow, sd)]     = *(const bf16x8*)vp;
      *(bf16x8*)&Vsh[srow * 64 + swz(srow, sd + 8)] = *(const bf16x8*)(vp + 8);
    }
    __syncthreads();
    if (act) {
      // S = Q K^T (16 x 64 per wave)
      f32x4 sc[4];
#pragma unroll
      for (int n = 0; n < 4; n++) {
        sc[n] = (f32x4){0.f, 0.f, 0.f, 0.f};
#pragma unroll
        for (int ks = 0; ks < 2; ks++) {
          int krow = n * 16 + l15;
          bf16x8 bk = *(const bf16x8*)&Ksh[krow * 64 + swz(krow, ks * 32 + lhi * 8)];
          sc[n] = __builtin_amdgcn_mfma_f32_16x16x32_bf16(aq[ks], bk, sc[n], 0, 0, 0);
        }
      }

      // online softmax
      const bool diag = (kt == qt);
      float fac[4];
      float p[4][4];
#pragma unroll
      for (int r = 0; r < 4; r++) {
        int rowg = qt * 64 + rw * 16 + lhi * 4 + r;
        float sv[4];
        float mx = -1e30f;
#pragma unroll
        for (int n = 0; n < 4; n++) {
          float v = sc[n][r] * 0.125f;  // 1/sqrt(64)
          int colg = kt * 64 + n * 16 + l15;
          if (diag && colg > rowg) v = -1e30f;
          sv[n] = v;
          mx = fmaxf(mx, v);
        }
#pragma unroll
        for (int msk = 1; msk < 16; msk <<= 1) mx = fmaxf(mx, __shfl_xor(mx, msk, 64));
        float mnew = fmaxf(mold[r], mx);
        float f = __expf(mold[r] - mnew);
        float ps = 0.f;
#pragma unroll
        for (int n = 0; n < 4; n++) {
          float e = __expf(sv[n] - mnew);
          p[n][r] = e;
          ps += e;
        }
#pragma unroll
        for (int msk = 1; msk < 16; msk <<= 1) ps += __shfl_xor(ps, msk, 64);
        lrow[r] = lrow[r] * f + ps;
        mold[r] = mnew;
        fac[r]  = f;
      }
#pragma unroll
      for (int n = 0; n < 4; n++) {
        o[n][0] *= fac[0]; o[n][1] *= fac[1]; o[n][2] *= fac[2]; o[n][3] *= fac[3];
      }

      // P: C-layout -> A-layout via per-wave LDS (padded [16][72])
#pragma unroll
      for (int n = 0; n < 4; n++)
#pragma unroll
        for (int r = 0; r < 4; r++)
          Psh[(lhi * 4 + r) * 72 + n * 16 + l15] = f2bf(p[n][r]);

      bf16x8 ap0 = *(const bf16x8*)&Psh[l15 * 72 + lhi * 8];
      bf16x8 ap1 = *(const bf16x8*)&Psh[l15 * 72 + 32 + lhi * 8];
#pragma unroll
      for (int n = 0; n < 4; n++) {
        int vrow = n * 16 + l15;
        bf16x8 bv0 = *(const bf16x8*)&Vsh[vrow * 64 + swz(vrow, lhi * 8)];
        bf16x8 bv1 = *(const bf16x8*)&Vsh[vrow * 64 + swz(vrow, 32 + lhi * 8)];
        o[n] = __builtin_amdgcn_mfma_f32_16x16x32_bf16(ap0, bv0, o[n], 0, 0, 0);
        o[n] = __builtin_amdgcn_mfma_f32_16x16x32_bf16(ap1, bv1, o[n], 0, 0, 0);
      }
    }
  }

  // ---- merge the two k-groups' partials (reuse pool; K/V dead) ----
  __syncthreads();
  f32x4* comb = (f32x4*)pool;
  const int ci = (rw * 64 + lane) * 6;
  if (g == 0) {
#pragma unroll
    for (int n = 0; n < 4; n++) comb[ci + n] = o[n];
    comb[ci + 4] = (f32x4){mold[0], mold[1], mold[2], mold[3]};
    comb[ci + 5] = (f32x4){lrow[0], lrow[1], lrow[2], lrow[3]};
  }
  __syncthreads();
  if (g == 1) {
    f32x4 m0 = comb[ci + 4];
    f32x4 l0 = comb[ci + 5];
    float a0[4], a1[4], inv[4];
#pragma unroll
    for (int r = 0; r < 4; r++) {
      float m = fmaxf(m0[r], mold[r]);
      a0[r] = __expf(m0[r] - m);
      a1[r] = __expf(mold[r] - m);
      float li = l0[r] * a0[r] + lrow[r] * a1[r];
      inv[r] = 1.0f / li;
    }
#pragma unroll
    for (int n = 0; n < 4; n++) {
      f32x4 o0 = comb[ci + n];
#pragma unroll
      for (int r = 0; r < 4; r++) {
        int rowg = qt * 64 + rw * 16 + lhi * 4 + r;
        float val = (o0[r] * a0[r] + o[n][r] * a1[r]) * inv[r];
        Aout[(((size_t)(b * SEQ + rowg)) << 10) + h * 64 + n * 16 + l15] = f2bf(val);
      }
    }
  }
}

// ---------------- launch ------------------------------------------------------
extern "C" void kernel_launch(void* const* d_in, const int* in_sizes, int n_in,
                              void* d_out, int out_size, void* d_ws, size_t ws_size,
                              hipStream_t stream) {
  const float* q  = (const float*)d_in[0];
  const float* k  = (const float*)d_in[1];
  const float* v  = (const float*)d_in[2];
  const float* Wq = (const float*)d_in[3];
  const float* bq = (const float*)d_in[4];
  const float* Wk = (const float*)d_in[5];
  const float* bk = (const float*)d_in[6];
  const float* Wv = (const float*)d_in[7];
  const float* bv = (const float*)d_in[8];
  const float* Wo = (const float*)d_in[9];
  const float* bo = (const float*)d_in[10];
  float* out = (float*)d_out;

  unsigned short* ws  = (unsigned short*)d_ws;
  unsigned short* wqb = ws;                       // 1M elems each
  unsigned short* wkb = ws + (1u << 20);
  unsigned short* wvb = ws + (2u << 20);
  unsigned short* wob = ws + (3u << 20);
  unsigned short* Qb  = ws + (4u << 20);          // [B,H,S,D]
  unsigned short* Kb  = ws + (8u << 20);          // [B,H,S,D]
  unsigned short* Vtb = ws + (12u << 20);         // [B,H,D,S]  (pre-transposed)
  unsigned short* Ab  = ws + (16u << 20);         // [B,S,H*D]

  cvt4_kernel<<<dim3(1024, 4), 256, 0, stream>>>(Wq, Wk, Wv, Wo, ws);

  gemm_kernel<0><<<dim3(32, 16), 256, 0, stream>>>((const void*)q, wqb, bq, (void*)Qb);
  gemm_kernel<0><<<dim3(32, 16), 256, 0, stream>>>((const void*)k, wkb, bk, (void*)Kb);
  gemm_kernel<2><<<dim3(32, 16), 256, 0, stream>>>((const void*)v, wvb, bv, (void*)Vtb);

  attn_kernel<<<dim3(32, 32), 512, 0, stream>>>(Qb, Kb, Vtb, Ab);

  gemm_kernel<1><<<dim3(32, 16), 256, 0, stream>>>((const void*)Ab, wob, bo, (void*)out);
}

// Round 3
// 138.592 us; speedup vs baseline: 2.3633x; 1.6829x over previous
//
#include <hip/hip_runtime.h>
#include <hip/hip_bf16.h>

// MHA forward, MI355X gfx950.
// cvt (weights + activations -> bf16) -> batched QKV proj GEMM (m97-style,
// global_load_lds, V pre-transposed) -> causal flash attn (swapped-QK in-register
// softmax, gll staging, XCD remap) -> out GEMM.
// HIDDEN=1024, HEADS=16, HEAD_DIM=64, B=2, S=2048.

typedef __attribute__((ext_vector_type(4))) float f32x4;
typedef __attribute__((ext_vector_type(8))) short bf16x8;
typedef unsigned short u16;

#define SEQ   2048
#define NH    16
#define HD    64
#define HID   1024
#define CEXP  0.1803368801f  // 0.125 * log2(e)
#define MEG   1048576u

static __device__ __forceinline__ u16 f2bf(float f) {
  union { float f; unsigned int u; } x; x.f = f;
  unsigned int r = x.u + 0x7fffu + ((x.u >> 16) & 1u);  // RNE
  return (u16)(r >> 16);
}

// XOR swizzle on 8-elem bf16 chunks within a 64-elem row (T2, G4).
static __device__ __forceinline__ int swz(int row, int col8) {
  return col8 ^ ((row & 7) << 3);
}

// async global->LDS, 16B per lane; lds dest must be wave-uniform (guide §5).
static __device__ __forceinline__ void gll16(const void* g, void* l) {
  __builtin_amdgcn_global_load_lds(
      (const __attribute__((address_space(1))) void*)g,
      (__attribute__((address_space(3))) void*)l, 16, 0, 0);
}

// ---------------- f32 -> bf16 conversion: 16 x 1M-elem slices ----------------
// y 0..3: Wq,Wk,Wv,Wo -> ws[0..4M); y 4..7: q -> ws[4M..8M);
// y 8..11: k -> d_out[0..4M); y 12..15: v -> d_out[4M..8M)
__global__ __launch_bounds__(256) void cvt_kernel(
    const float* __restrict__ Wq, const float* __restrict__ Wk,
    const float* __restrict__ Wv, const float* __restrict__ Wo,
    const float* __restrict__ q, const float* __restrict__ k,
    const float* __restrict__ v,
    u16* __restrict__ wsout, u16* __restrict__ dob) {
  const int y = blockIdx.y;
  const int c = y & 3;
  const float* src;
  u16* dst;
  if (y < 4) {
    src = (y == 0) ? Wq : (y == 1) ? Wk : (y == 2) ? Wv : Wo;
    dst = wsout + (size_t)y * MEG;
  } else if (y < 8) {
    src = q + (size_t)c * MEG;
    dst = wsout + 4u * MEG + (size_t)c * MEG;
  } else if (y < 12) {
    src = k + (size_t)c * MEG;
    dst = dob + (size_t)c * MEG;
  } else {
    src = v + (size_t)c * MEG;
    dst = dob + 4u * MEG + (size_t)c * MEG;
  }
  int i = (blockIdx.x * 256 + threadIdx.x) * 4;
  float4 f = *(const float4*)(src + i);
  ushort4 o;
  o.x = f2bf(f.x); o.y = f2bf(f.y); o.z = f2bf(f.z); o.w = f2bf(f.w);
  *(ushort4*)(dst + i) = o;
}

// -------- batched QKV projection: C = X @ W^T + b, scatter to heads ----------
// z=0: Q -> [B,H,S,D]; z=1: K -> [B,H,S,D]; z=2: V -> [B,H,D,S] (transposed).
// 128x128 tile, BK=64, 256 thr = 4 waves (2x2), global_load_lds staging (m97).
__global__ __launch_bounds__(256) void proj_kernel(
    const u16* __restrict__ Xq, const u16* __restrict__ Xk,
    const u16* __restrict__ Xv, const u16* __restrict__ Wc,
    const float* __restrict__ bq, const float* __restrict__ bk,
    const float* __restrict__ bvp,
    u16* __restrict__ Qo, u16* __restrict__ Ko, u16* __restrict__ Vto) {
  __shared__ u16 As[128 * 64];
  __shared__ u16 Bs[128 * 64];

  const int tid  = threadIdx.x;
  const int lane = tid & 63;
  const int wid  = tid >> 6;
  const int wm   = wid >> 1, wn = wid & 1;
  const int l15  = lane & 15;
  const int lhi  = lane >> 4;
  const int z    = blockIdx.z;
  const int bm   = blockIdx.x * 128;
  const int bn   = blockIdx.y * 128;

  const u16* X = (z == 0) ? Xq : (z == 1) ? Xk : Xv;
  const u16* W = Wc + (size_t)z * (HID * HID);
  const float* bias = (z == 0) ? bq : (z == 1) ? bk : bvp;

  f32x4 acc[4][4];
#pragma unroll
  for (int i = 0; i < 4; i++)
#pragma unroll
    for (int j = 0; j < 4; j++) acc[i][j] = (f32x4){0.f, 0.f, 0.f, 0.f};

  const int lrow = lane >> 3;      // 0..7
  const int lcol = (lane & 7) * 8; // elem offset

  for (int k0 = 0; k0 < HID; k0 += 64) {
#pragma unroll
    for (int c = 0; c < 4; c++) {
      const int row = c * 32 + wid * 8 + lrow;
      gll16(X + (size_t)(bm + row) * HID + k0 + lcol, (char*)As + c * 4096 + wid * 1024);
      gll16(W + (size_t)(bn + row) * HID + k0 + lcol, (char*)Bs + c * 4096 + wid * 1024);
    }
    __syncthreads();
#pragma unroll
    for (int ks = 0; ks < 2; ks++) {
      bf16x8 af[4], bfm[4];
#pragma unroll
      for (int i = 0; i < 4; i++)
        af[i] = *(const bf16x8*)&As[(wm * 64 + i * 16 + l15) * 64 + ks * 32 + lhi * 8];
#pragma unroll
      for (int j = 0; j < 4; j++)
        bfm[j] = *(const bf16x8*)&Bs[(wn * 64 + j * 16 + l15) * 64 + ks * 32 + lhi * 8];
#pragma unroll
      for (int i = 0; i < 4; i++)
#pragma unroll
        for (int j = 0; j < 4; j++)
          acc[i][j] = __builtin_amdgcn_mfma_f32_16x16x32_bf16(af[i], bfm[j], acc[i][j], 0, 0, 0);
    }
    __syncthreads();
  }

  // epilogue: bias + scatter
  const int bb = bm >> 11;  // batch of this tile (tile never crosses batch)
#pragma unroll
  for (int j = 0; j < 4; j++) {
    const int n = bn + wn * 64 + j * 16 + l15;
    const float bv_ = bias[n];
    const int h = n >> 6, d = n & 63;
    if (z == 2) {
#pragma unroll
      for (int i = 0; i < 4; i++) {
        const int s0 = (bm + wm * 64 + i * 16 + lhi * 4) & 2047;
        ushort4 t;
        t.x = f2bf(acc[i][j][0] + bv_);
        t.y = f2bf(acc[i][j][1] + bv_);
        t.z = f2bf(acc[i][j][2] + bv_);
        t.w = f2bf(acc[i][j][3] + bv_);
        *(ushort4*)&Vto[((size_t)(bb * NH + h) * HD + d) * SEQ + s0] = t;
      }
    } else {
      u16* O = z ? Ko : Qo;
#pragma unroll
      for (int i = 0; i < 4; i++)
#pragma unroll
        for (int r = 0; r < 4; r++) {
          const int m = bm + wm * 64 + i * 16 + lhi * 4 + r;
          const int s = m & 2047;
          O[(((size_t)(bb * NH + h) * SEQ + s) << 6) + d] = f2bf(acc[i][j][r] + bv_);
        }
    }
  }
}

// ---------------- causal flash attention -------------------------------------
// Q,K: bf16 [B,H,S,D]; Vt: bf16 [B,H,D,S]; out: bf16 [B,S,H*D].
// 512 thr = 2 k-groups x 4 row-waves; swapped QK^T (lane = one q-row, 16 k in reg).
__global__ __launch_bounds__(512) void attn_kernel(
    const u16* __restrict__ Q, const u16* __restrict__ K,
    const u16* __restrict__ Vt, u16* __restrict__ Aout) {
  // Ksh[g] @ g*8192, Vsh[g] @ 16384+g*8192 (each [64][64] swizzled),
  // Psh[w] @ 32768+wid*2304 ([16][72]). total 51200 B -> 3 blocks/CU.
  __shared__ __align__(16) char pool[51200];

  const int tid  = threadIdx.x;
  const int lane = tid & 63;
  const int wid  = tid >> 6;
  const int rw   = wid & 3;
  const int g    = wid >> 2;
  const int l15  = lane & 15;
  const int lhi  = lane >> 4;

  // XCD-locality remap (T1): xcd = flat&7 gets bh in {4*xcd..4*xcd+3}, all qt.
  const int flat = blockIdx.x;
  const int slot = flat >> 3;
  const int bh   = (flat & 7) * 4 + (slot & 3);
  const int qt   = slot >> 2;
  const int b    = bh >> 4, h = bh & 15;
  const size_t base = (size_t)bh * SEQ * HD;

  u16* Ksh = (u16*)(pool + g * 8192);
  u16* Vsh = (u16*)(pool + 16384 + g * 8192);
  u16* Psh = (u16*)(pool + 32768 + wid * 2304);

  const int qrow = qt * 64 + rw * 16 + l15;  // this lane's q-row
  bf16x8 aq[2];
  aq[0] = *(const bf16x8*)&Q[base + (size_t)qrow * HD + lhi * 8];
  aq[1] = *(const bf16x8*)&Q[base + (size_t)qrow * HD + 32 + lhi * 8];

  f32x4 o[4];
#pragma unroll
  for (int n = 0; n < 4; n++) o[n] = (f32x4){0.f, 0.f, 0.f, 0.f};
  float m_s = -1e30f, l_s = 0.f;

  const int grow = lane >> 3;               // gll staging row-within-8
  const int gcol = lane & 7;

  const int nsteps = qt / 2 + 1;
  for (int it = 0; it < nsteps; ++it) {
    const int kt = 2 * it + g;
    const bool act = (kt <= qt);
    __syncthreads();  // prior LDS reads done before overwrite
    if (act) {
#pragma unroll
      for (int j = 0; j < 2; j++) {
        const int row = j * 32 + rw * 8 + grow;
        const int scv = (gcol ^ (row & 7)) * 8;  // pre-swizzled source (rule 21)
        gll16(K + base + (size_t)(kt * 64 + row) * HD + scv,
              (char*)Ksh + j * 4096 + rw * 1024);
        gll16(Vt + base + (size_t)row * SEQ + kt * 64 + scv,
              (char*)Vsh + j * 4096 + rw * 1024);
      }
    }
    __syncthreads();
    if (act) {
      // S^T = mfma(K, Q): lane holds q=qrow, k = kt*64 + n*16 + lhi*4 + r
      f32x4 sc[4];
#pragma unroll
      for (int n = 0; n < 4; n++) {
        sc[n] = (f32x4){0.f, 0.f, 0.f, 0.f};
#pragma unroll
        for (int ks = 0; ks < 2; ks++) {
          const int krow = n * 16 + l15;
          bf16x8 bk = *(const bf16x8*)&Ksh[krow * 64 + swz(krow, ks * 32 + lhi * 8)];
          sc[n] = __builtin_amdgcn_mfma_f32_16x16x32_bf16(bk, aq[ks], sc[n], 0, 0, 0);
        }
      }
      if (kt == qt) {  // causal mask, diagonal tile only
#pragma unroll
        for (int n = 0; n < 4; n++)
#pragma unroll
          for (int r = 0; r < 4; r++)
            if (kt * 64 + n * 16 + lhi * 4 + r > qrow) sc[n][r] = -1e30f;
      }
      // in-register online softmax (raw scores; scale folded into exp2)
      float mx = -1e30f;
#pragma unroll
      for (int n = 0; n < 4; n++)
#pragma unroll
        for (int r = 0; r < 4; r++) mx = fmaxf(mx, sc[n][r]);
      mx = fmaxf(mx, __shfl_xor(mx, 16, 64));
      mx = fmaxf(mx, __shfl_xor(mx, 32, 64));
      const float mnew = fmaxf(m_s, mx);
      const float fac = __builtin_amdgcn_exp2f((m_s - mnew) * CEXP);
      float ps = 0.f;
      u16 pb[4][4];
#pragma unroll
      for (int n = 0; n < 4; n++)
#pragma unroll
        for (int r = 0; r < 4; r++) {
          const float e = __builtin_amdgcn_exp2f((sc[n][r] - mnew) * CEXP);
          ps += e;
          pb[n][r] = f2bf(e);
        }
      ps += __shfl_xor(ps, 16, 64);
      ps += __shfl_xor(ps, 32, 64);
      l_s = l_s * fac + ps;
      m_s = mnew;
      // gather rescale factors into o-layout (row = lhi*4+r)
      float facr[4];
#pragma unroll
      for (int r = 0; r < 4; r++) facr[r] = __shfl(fac, lhi * 4 + r, 64);
#pragma unroll
      for (int n = 0; n < 4; n++) {
        o[n][0] *= facr[0]; o[n][1] *= facr[1];
        o[n][2] *= facr[2]; o[n][3] *= facr[3];
      }
      // P -> LDS (packed ushort4: k = n*16 + lhi*4 + r contiguous in r)
#pragma unroll
      for (int n = 0; n < 4; n++) {
        ushort4 t; t.x = pb[n][0]; t.y = pb[n][1]; t.z = pb[n][2]; t.w = pb[n][3];
        *(ushort4*)&Psh[l15 * 72 + n * 16 + lhi * 4] = t;
      }
      bf16x8 ap0 = *(const bf16x8*)&Psh[l15 * 72 + lhi * 8];
      bf16x8 ap1 = *(const bf16x8*)&Psh[l15 * 72 + 32 + lhi * 8];
#pragma unroll
      for (int n = 0; n < 4; n++) {
        const int vrow = n * 16 + l15;
        bf16x8 bv0 = *(const bf16x8*)&Vsh[vrow * 64 + swz(vrow, lhi * 8)];
        bf16x8 bv1 = *(const bf16x8*)&Vsh[vrow * 64 + swz(vrow, 32 + lhi * 8)];
        o[n] = __builtin_amdgcn_mfma_f32_16x16x32_bf16(ap0, bv0, o[n], 0, 0, 0);
        o[n] = __builtin_amdgcn_mfma_f32_16x16x32_bf16(ap1, bv1, o[n], 0, 0, 0);
      }
    }
  }

  __syncthreads();
  // redistribute per-q-row state (held at lane l15=q) into o-layout rows
  float m_o[4], l_o[4];
#pragma unroll
  for (int r = 0; r < 4; r++) {
    m_o[r] = __shfl(m_s, lhi * 4 + r, 64);
    l_o[r] = __shfl(l_s, lhi * 4 + r, 64);
  }

  // merge k-group partials (pool reused; K/V/P dead)
  f32x4* comb = (f32x4*)pool;
  const int ci = (rw * 64 + lane) * 6;
  if (g == 0) {
#pragma unroll
    for (int n = 0; n < 4; n++) comb[ci + n] = o[n];
    comb[ci + 4] = (f32x4){m_o[0], m_o[1], m_o[2], m_o[3]};
    comb[ci + 5] = (f32x4){l_o[0], l_o[1], l_o[2], l_o[3]};
  }
  __syncthreads();
  if (g == 1) {
    f32x4 m0 = comb[ci + 4];
    f32x4 l0 = comb[ci + 5];
    float a0[4], a1[4], inv[4];
#pragma unroll
    for (int r = 0; r < 4; r++) {
      const float m = fmaxf(m0[r], m_o[r]);
      a0[r] = __builtin_amdgcn_exp2f((m0[r] - m) * CEXP);
      a1[r] = __builtin_amdgcn_exp2f((m_o[r] - m) * CEXP);
      inv[r] = 1.0f / (l0[r] * a0[r] + l_o[r] * a1[r]);
    }
#pragma unroll
    for (int n = 0; n < 4; n++) {
      f32x4 o0 = comb[ci + n];
#pragma unroll
      for (int r = 0; r < 4; r++) {
        const int rowg = qt * 64 + rw * 16 + lhi * 4 + r;
        const float val = (o0[r] * a0[r] + o[n][r] * a1[r]) * inv[r];
        Aout[(((size_t)(b * SEQ + rowg)) << 10) + h * 64 + n * 16 + l15] = f2bf(val);
      }
    }
  }
}

// ---------------- out projection: f32 out = Ab @ Wo^T + bo -------------------
// 128x64 tile, BK=64, 256 thr = 4 waves, gll staging. grid (32,16) = 2/CU.
__global__ __launch_bounds__(256) void oproj_kernel(
    const u16* __restrict__ X, const u16* __restrict__ W,
    const float* __restrict__ bias, float* __restrict__ Out) {
  __shared__ u16 As[128 * 64];
  __shared__ u16 Bs[64 * 64];

  const int tid  = threadIdx.x;
  const int lane = tid & 63;
  const int wid  = tid >> 6;
  const int wm   = wid >> 1, wn = wid & 1;
  const int l15  = lane & 15;
  const int lhi  = lane >> 4;
  const int bm   = blockIdx.x * 128;
  const int bn   = blockIdx.y * 64;

  f32x4 acc[4][2];
#pragma unroll
  for (int i = 0; i < 4; i++)
#pragma unroll
    for (int j = 0; j < 2; j++) acc[i][j] = (f32x4){0.f, 0.f, 0.f, 0.f};

  const int lrow = lane >> 3;
  const int lcol = (lane & 7) * 8;

  for (int k0 = 0; k0 < HID; k0 += 64) {
#pragma unroll
    for (int c = 0; c < 4; c++) {
      const int row = c * 32 + wid * 8 + lrow;
      gll16(X + (size_t)(bm + row) * HID + k0 + lcol, (char*)As + c * 4096 + wid * 1024);
      if (c < 2)
        gll16(W + (size_t)(bn + row) * HID + k0 + lcol, (char*)Bs + c * 4096 + wid * 1024);
    }
    __syncthreads();
#pragma unroll
    for (int ks = 0; ks < 2; ks++) {
      bf16x8 af[4], bfm[2];
#pragma unroll
      for (int i = 0; i < 4; i++)
        af[i] = *(const bf16x8*)&As[(wm * 64 + i * 16 + l15) * 64 + ks * 32 + lhi * 8];
#pragma unroll
      for (int j = 0; j < 2; j++)
        bfm[j] = *(const bf16x8*)&Bs[(wn * 32 + j * 16 + l15) * 64 + ks * 32 + lhi * 8];
#pragma unroll
      for (int i = 0; i < 4; i++)
#pragma unroll
        for (int j = 0; j < 2; j++)
          acc[i][j] = __builtin_amdgcn_mfma_f32_16x16x32_bf16(af[i], bfm[j], acc[i][j], 0, 0, 0);
    }
    __syncthreads();
  }

#pragma unroll
  for (int j = 0; j < 2; j++) {
    const int n = bn + wn * 32 + j * 16 + l15;
    const float bv_ = bias[n];
#pragma unroll
    for (int i = 0; i < 4; i++)
#pragma unroll
      for (int r = 0; r < 4; r++) {
        const int m = bm + wm * 64 + i * 16 + lhi * 4 + r;
        Out[(size_t)m * HID + n] = acc[i][j][r] + bv_;
      }
  }
}

// ---------------- launch ------------------------------------------------------
extern "C" void kernel_launch(void* const* d_in, const int* in_sizes, int n_in,
                              void* d_out, int out_size, void* d_ws, size_t ws_size,
                              hipStream_t stream) {
  const float* q  = (const float*)d_in[0];
  const float* k  = (const float*)d_in[1];
  const float* v  = (const float*)d_in[2];
  const float* Wq = (const float*)d_in[3];
  const float* bq = (const float*)d_in[4];
  const float* Wk = (const float*)d_in[5];
  const float* bk = (const float*)d_in[6];
  const float* Wv = (const float*)d_in[7];
  const float* bv = (const float*)d_in[8];
  const float* Wo = (const float*)d_in[9];
  const float* bo = (const float*)d_in[10];

  u16* ws   = (u16*)d_ws;
  u16* wqkv = ws;                    // Wq,Wk,Wv bf16 @ 0,1M,2M
  u16* wob  = ws + 3u * MEG;         // Wo bf16
  u16* qb   = ws + 4u * MEG;         // q bf16 (4M elems); later reused as Ab
  u16* Qb   = ws + 8u * MEG;         // [B,H,S,D]
  u16* Kb   = ws + 12u * MEG;        // [B,H,S,D]
  u16* Vtb  = ws + 16u * MEG;        // [B,H,D,S]
  u16* Ab   = qb;                    // attn out [B,S,H*D] (qb dead after proj)
  u16* kbf  = (u16*)d_out;           // k bf16 lives in d_out scratch (4M elems)
  u16* vbf  = (u16*)d_out + 4u * MEG;// v bf16 (4M elems) — d_out = 8M u16 total

  cvt_kernel<<<dim3(1024, 16), 256, 0, stream>>>(Wq, Wk, Wv, Wo, q, k, v, ws, kbf);

  proj_kernel<<<dim3(32, 8, 3), 256, 0, stream>>>(qb, kbf, vbf, wqkv, bq, bk, bv,
                                                  Qb, Kb, Vtb);

  attn_kernel<<<dim3(1024), 512, 0, stream>>>(Qb, Kb, Vtb, Ab);

  oproj_kernel<<<dim3(32, 16), 256, 0, stream>>>(Ab, wob, bo, (float*)d_out);
}

// Round 4
// 137.383 us; speedup vs baseline: 2.3841x; 1.0088x over previous
//
#include <hip/hip_runtime.h>
#include <hip/hip_bf16.h>

// MHA forward, MI355X gfx950.
// cvt (weights+activations -> bf16) -> batched QKV proj GEMM (2-phase dbuf,
// swizzled LDS, global_load_lds) -> causal flash attn (swapped-QK in-register
// softmax, dbuf prefetch, XCD remap) -> out GEMM (2-phase dbuf).
// HIDDEN=1024, HEADS=16, HEAD_DIM=64, B=2, S=2048.

typedef __attribute__((ext_vector_type(4))) float f32x4;
typedef __attribute__((ext_vector_type(8))) short bf16x8;
typedef unsigned short u16;

#define SEQ   2048
#define NH    16
#define HD    64
#define HID   1024
#define CEXP  0.1803368801f  // 0.125 * log2(e)
#define MEG   1048576u

static __device__ __forceinline__ u16 f2bf(float f) {
  union { float f; unsigned int u; } x; x.f = f;
  unsigned int r = x.u + 0x7fffu + ((x.u >> 16) & 1u);  // RNE
  return (u16)(r >> 16);
}

// XOR swizzle on 8-elem bf16 chunks within a 64-elem row (T2, G4).
static __device__ __forceinline__ int swz(int row, int col8) {
  return col8 ^ ((row & 7) << 3);
}

// async global->LDS, 16B/lane; lds dest wave-uniform base (guide §5).
static __device__ __forceinline__ void gll16(const void* g, void* l) {
  __builtin_amdgcn_global_load_lds(
      (const __attribute__((address_space(1))) void*)g,
      (__attribute__((address_space(3))) void*)l, 16, 0, 0);
}

// ---------------- f32 -> bf16 conversion: 16 x 1M-elem slices ----------------
__global__ __launch_bounds__(256) void cvt_kernel(
    const float* __restrict__ Wq, const float* __restrict__ Wk,
    const float* __restrict__ Wv, const float* __restrict__ Wo,
    const float* __restrict__ q, const float* __restrict__ k,
    const float* __restrict__ v,
    u16* __restrict__ wsout, u16* __restrict__ dob) {
  const int y = blockIdx.y;
  const int c = y & 3;
  const float* src;
  u16* dst;
  if (y < 4) {
    src = (y == 0) ? Wq : (y == 1) ? Wk : (y == 2) ? Wv : Wo;
    dst = wsout + (size_t)y * MEG;
  } else if (y < 8) {
    src = q + (size_t)c * MEG;
    dst = wsout + 4u * MEG + (size_t)c * MEG;
  } else if (y < 12) {
    src = k + (size_t)c * MEG;
    dst = dob + (size_t)c * MEG;
  } else {
    src = v + (size_t)c * MEG;
    dst = dob + 4u * MEG + (size_t)c * MEG;
  }
  int i = (blockIdx.x * 256 + threadIdx.x) * 4;
  float4 f = *(const float4*)(src + i);
  ushort4 o;
  o.x = f2bf(f.x); o.y = f2bf(f.y); o.z = f2bf(f.z); o.w = f2bf(f.w);
  *(ushort4*)(dst + i) = o;
}

// -------- batched QKV projection: C = X @ W^T + b, scatter to heads ----------
// z=0: Q -> [B,H,S,D]; z=1: K -> [B,H,S,D]; z=2: V -> [B,H,D,S] (transposed).
// 128x128 tile, BK=64, 2-phase double-buffered gll staging, swizzled LDS.
__global__ __launch_bounds__(256) void proj_kernel(
    const u16* __restrict__ Xq, const u16* __restrict__ Xk,
    const u16* __restrict__ Xv, const u16* __restrict__ Wc,
    const float* __restrict__ bq, const float* __restrict__ bk,
    const float* __restrict__ bvp,
    u16* __restrict__ Qo, u16* __restrict__ Ko, u16* __restrict__ Vto) {
  __shared__ u16 As[2][128 * 64];
  __shared__ u16 Bs[2][128 * 64];

  const int tid  = threadIdx.x;
  const int lane = tid & 63;
  const int wid  = tid >> 6;
  const int wm   = wid >> 1, wn = wid & 1;
  const int l15  = lane & 15;
  const int lhi  = lane >> 4;
  const int z    = blockIdx.z;
  const int bm   = blockIdx.x * 128;
  const int bn   = blockIdx.y * 128;

  const u16* X = (z == 0) ? Xq : (z == 1) ? Xk : Xv;
  const u16* W = Wc + (size_t)z * (HID * HID);
  const float* bias = (z == 0) ? bq : (z == 1) ? bk : bvp;

  f32x4 acc[4][4];
#pragma unroll
  for (int i = 0; i < 4; i++)
#pragma unroll
    for (int j = 0; j < 4; j++) acc[i][j] = (f32x4){0.f, 0.f, 0.f, 0.f};

  const int lrow  = lane >> 3;      // 0..7
  const int gcol8 = lane & 7;       // 8-elem chunk index

#define PROJ_STAGE(buf, k0)                                                       \
  {                                                                               \
    _Pragma("unroll")                                                             \
    for (int c = 0; c < 4; c++) {                                                 \
      const int row  = c * 32 + wid * 8 + lrow;                                   \
      const int scol = (gcol8 ^ (row & 7)) * 8; /* inverse-swizzled source */     \
      gll16(X + (size_t)(bm + row) * HID + (k0) + scol,                           \
            (char*)&As[buf][0] + c * 4096 + wid * 1024);                          \
      gll16(W + (size_t)(bn + row) * HID + (k0) + scol,                           \
            (char*)&Bs[buf][0] + c * 4096 + wid * 1024);                          \
    }                                                                             \
  }

  PROJ_STAGE(0, 0);
  for (int t = 0; t < 16; t++) {
    __syncthreads();  // drains vmcnt for buf[t&1]; prior reads of buf[(t+1)&1] done
    if (t < 15) PROJ_STAGE((t + 1) & 1, (t + 1) * 64);
    const u16* A = &As[t & 1][0];
    const u16* B = &Bs[t & 1][0];
#pragma unroll
    for (int ks = 0; ks < 2; ks++) {
      bf16x8 af[4], bfm[4];
#pragma unroll
      for (int i = 0; i < 4; i++) {
        const int row = wm * 64 + i * 16 + l15;
        af[i] = *(const bf16x8*)&A[row * 64 + swz(row, ks * 32 + lhi * 8)];
      }
#pragma unroll
      for (int j = 0; j < 4; j++) {
        const int row = wn * 64 + j * 16 + l15;
        bfm[j] = *(const bf16x8*)&B[row * 64 + swz(row, ks * 32 + lhi * 8)];
      }
#pragma unroll
      for (int i = 0; i < 4; i++)
#pragma unroll
        for (int j = 0; j < 4; j++)
          acc[i][j] = __builtin_amdgcn_mfma_f32_16x16x32_bf16(af[i], bfm[j], acc[i][j], 0, 0, 0);
    }
  }

  // epilogue: bias + scatter to heads
  const int bb = bm >> 11;  // tile never crosses batch
#pragma unroll
  for (int j = 0; j < 4; j++) {
    const int n = bn + wn * 64 + j * 16 + l15;
    const float bv_ = bias[n];
    const int h = n >> 6, d = n & 63;
    if (z == 2) {
#pragma unroll
      for (int i = 0; i < 4; i++) {
        const int s0 = (bm + wm * 64 + i * 16 + lhi * 4) & 2047;
        ushort4 t;
        t.x = f2bf(acc[i][j][0] + bv_);
        t.y = f2bf(acc[i][j][1] + bv_);
        t.z = f2bf(acc[i][j][2] + bv_);
        t.w = f2bf(acc[i][j][3] + bv_);
        *(ushort4*)&Vto[((size_t)(bb * NH + h) * HD + d) * SEQ + s0] = t;
      }
    } else {
      u16* O = z ? Ko : Qo;
#pragma unroll
      for (int i = 0; i < 4; i++)
#pragma unroll
        for (int r = 0; r < 4; r++) {
          const int m = bm + wm * 64 + i * 16 + lhi * 4 + r;
          const int s = m & 2047;
          O[(((size_t)(bb * NH + h) * SEQ + s) << 6) + d] = f2bf(acc[i][j][r] + bv_);
        }
    }
  }
#undef PROJ_STAGE
}

// ---------------- causal flash attention -------------------------------------
// Q,K: bf16 [B,H,S,D]; Vt: bf16 [B,H,D,S]; out: bf16 [B,S,H*D].
// 512 thr = 2 k-groups x 4 row-waves; swapped QK^T; K/V double-buffered prefetch.
__global__ __launch_bounds__(512) void attn_kernel(
    const u16* __restrict__ Q, const u16* __restrict__ K,
    const u16* __restrict__ Vt, u16* __restrict__ Aout) {
  // K[g][buf] @ (g*2+buf)*8192 (0..32K), V[g][buf] @ 32768+(g*2+buf)*8192
  // (32..64K), Psh[w] @ 65536+wid*2304. total 83968 B -> 1 block/CU.
  __shared__ __align__(16) char pool[83968];

  const int tid  = threadIdx.x;
  const int lane = tid & 63;
  const int wid  = tid >> 6;
  const int rw   = wid & 3;
  const int g    = wid >> 2;
  const int l15  = lane & 15;
  const int lhi  = lane >> 4;

  // XCD-locality remap (T1)
  const int flat = blockIdx.x;
  const int slot = flat >> 3;
  const int bh   = (flat & 7) * 4 + (slot & 3);
  const int qt   = slot >> 2;
  const int b    = bh >> 4, h = bh & 15;
  const size_t base = (size_t)bh * SEQ * HD;

  char* Kb0 = pool + g * 16384;
  char* Vb0 = pool + 32768 + g * 16384;
  u16*  Psh = (u16*)(pool + 65536 + wid * 2304);

  const int qrow = qt * 64 + rw * 16 + l15;
  bf16x8 aq[2];
  aq[0] = *(const bf16x8*)&Q[base + (size_t)qrow * HD + lhi * 8];
  aq[1] = *(const bf16x8*)&Q[base + (size_t)qrow * HD + 32 + lhi * 8];

  f32x4 o[4];
#pragma unroll
  for (int n = 0; n < 4; n++) o[n] = (f32x4){0.f, 0.f, 0.f, 0.f};
  float m_s = -1e30f, l_s = 0.f;

  const int grow = lane >> 3;
  const int gcol = lane & 7;

#define ATTN_STAGE(buf, kt_)                                                      \
  {                                                                               \
    _Pragma("unroll")                                                             \
    for (int j = 0; j < 2; j++) {                                                 \
      const int row = j * 32 + rw * 8 + grow;                                     \
      const int scv = (gcol ^ (row & 7)) * 8;                                     \
      gll16(K + base + (size_t)((kt_) * 64 + row) * HD + scv,                     \
            Kb0 + (buf) * 8192 + j * 4096 + rw * 1024);                           \
      gll16(Vt + base + (size_t)row * SEQ + (kt_) * 64 + scv,                     \
            Vb0 + (buf) * 8192 + j * 4096 + rw * 1024);                           \
    }                                                                             \
  }

  if (g <= qt) ATTN_STAGE(0, g);

  int buf = 0;
  const int nsteps = qt / 2 + 1;
  for (int it = 0; it < nsteps; ++it) {
    const int kt = 2 * it + g;
    const bool act = (kt <= qt);
    __syncthreads();  // drains vmcnt(prefetch) + prior LDS reads
    const int ktn = kt + 2;
    if (ktn <= qt) ATTN_STAGE(buf ^ 1, ktn);
    if (act) {
      const u16* Ksh = (const u16*)(Kb0 + buf * 8192);
      const u16* Vsh = (const u16*)(Vb0 + buf * 8192);
      // S^T = mfma(K, Q): lane l15 = q-row; regs hold k = kt*64 + n*16 + lhi*4 + r
      f32x4 sc[4];
#pragma unroll
      for (int n = 0; n < 4; n++) {
        sc[n] = (f32x4){0.f, 0.f, 0.f, 0.f};
#pragma unroll
        for (int ks = 0; ks < 2; ks++) {
          const int krow = n * 16 + l15;
          bf16x8 bk = *(const bf16x8*)&Ksh[krow * 64 + swz(krow, ks * 32 + lhi * 8)];
          sc[n] = __builtin_amdgcn_mfma_f32_16x16x32_bf16(bk, aq[ks], sc[n], 0, 0, 0);
        }
      }
      if (kt == qt) {  // causal mask on diagonal tile
#pragma unroll
        for (int n = 0; n < 4; n++)
#pragma unroll
          for (int r = 0; r < 4; r++)
            if (kt * 64 + n * 16 + lhi * 4 + r > qrow) sc[n][r] = -1e30f;
      }
      // in-register online softmax
      float mx = -1e30f;
#pragma unroll
      for (int n = 0; n < 4; n++)
#pragma unroll
        for (int r = 0; r < 4; r++) mx = fmaxf(mx, sc[n][r]);
      mx = fmaxf(mx, __shfl_xor(mx, 16, 64));
      mx = fmaxf(mx, __shfl_xor(mx, 32, 64));
      const float mnew = fmaxf(m_s, mx);
      const float fac = __builtin_amdgcn_exp2f((m_s - mnew) * CEXP);
      float ps = 0.f;
      u16 pb[4][4];
#pragma unroll
      for (int n = 0; n < 4; n++)
#pragma unroll
        for (int r = 0; r < 4; r++) {
          const float e = __builtin_amdgcn_exp2f((sc[n][r] - mnew) * CEXP);
          ps += e;
          pb[n][r] = f2bf(e);
        }
      ps += __shfl_xor(ps, 16, 64);
      ps += __shfl_xor(ps, 32, 64);
      l_s = l_s * fac + ps;
      m_s = mnew;
      float facr[4];
#pragma unroll
      for (int r = 0; r < 4; r++) facr[r] = __shfl(fac, lhi * 4 + r, 64);
#pragma unroll
      for (int n = 0; n < 4; n++) {
        o[n][0] *= facr[0]; o[n][1] *= facr[1];
        o[n][2] *= facr[2]; o[n][3] *= facr[3];
      }
      // P -> per-wave LDS -> A-frag
#pragma unroll
      for (int n = 0; n < 4; n++) {
        ushort4 t; t.x = pb[n][0]; t.y = pb[n][1]; t.z = pb[n][2]; t.w = pb[n][3];
        *(ushort4*)&Psh[l15 * 72 + n * 16 + lhi * 4] = t;
      }
      bf16x8 ap0 = *(const bf16x8*)&Psh[l15 * 72 + lhi * 8];
      bf16x8 ap1 = *(const bf16x8*)&Psh[l15 * 72 + 32 + lhi * 8];
#pragma unroll
      for (int n = 0; n < 4; n++) {
        const int vrow = n * 16 + l15;
        bf16x8 bv0 = *(const bf16x8*)&Vsh[vrow * 64 + swz(vrow, lhi * 8)];
        bf16x8 bv1 = *(const bf16x8*)&Vsh[vrow * 64 + swz(vrow, 32 + lhi * 8)];
        o[n] = __builtin_amdgcn_mfma_f32_16x16x32_bf16(ap0, bv0, o[n], 0, 0, 0);
        o[n] = __builtin_amdgcn_mfma_f32_16x16x32_bf16(ap1, bv1, o[n], 0, 0, 0);
      }
    }
    buf ^= 1;
  }
#undef ATTN_STAGE

  __syncthreads();
  float m_o[4], l_o[4];
#pragma unroll
  for (int r = 0; r < 4; r++) {
    m_o[r] = __shfl(m_s, lhi * 4 + r, 64);
    l_o[r] = __shfl(l_s, lhi * 4 + r, 64);
  }

  // merge the two k-groups' partials (pool reused; K buffers dead)
  f32x4* comb = (f32x4*)pool;
  const int ci = (rw * 64 + lane) * 6;
  if (g == 0) {
#pragma unroll
    for (int n = 0; n < 4; n++) comb[ci + n] = o[n];
    comb[ci + 4] = (f32x4){m_o[0], m_o[1], m_o[2], m_o[3]};
    comb[ci + 5] = (f32x4){l_o[0], l_o[1], l_o[2], l_o[3]};
  }
  __syncthreads();
  if (g == 1) {
    f32x4 m0 = comb[ci + 4];
    f32x4 l0 = comb[ci + 5];
    float a0[4], a1[4], inv[4];
#pragma unroll
    for (int r = 0; r < 4; r++) {
      const float m = fmaxf(m0[r], m_o[r]);
      a0[r] = __builtin_amdgcn_exp2f((m0[r] - m) * CEXP);
      a1[r] = __builtin_amdgcn_exp2f((m_o[r] - m) * CEXP);
      inv[r] = 1.0f / (l0[r] * a0[r] + l_o[r] * a1[r]);
    }
#pragma unroll
    for (int n = 0; n < 4; n++) {
      f32x4 o0 = comb[ci + n];
#pragma unroll
      for (int r = 0; r < 4; r++) {
        const int rowg = qt * 64 + rw * 16 + lhi * 4 + r;
        const float val = (o0[r] * a0[r] + o[n][r] * a1[r]) * inv[r];
        Aout[(((size_t)(b * SEQ + rowg)) << 10) + h * 64 + n * 16 + l15] = f2bf(val);
      }
    }
  }
}

// ---------------- out projection: f32 out = Ab @ Wo^T + bo -------------------
// 128x64 tile, BK=64, 2-phase dbuf, swizzled. grid (32,16) = 2/CU.
__global__ __launch_bounds__(256) void oproj_kernel(
    const u16* __restrict__ X, const u16* __restrict__ W,
    const float* __restrict__ bias, float* __restrict__ Out) {
  __shared__ u16 As[2][128 * 64];
  __shared__ u16 Bs[2][64 * 64];

  const int tid  = threadIdx.x;
  const int lane = tid & 63;
  const int wid  = tid >> 6;
  const int wm   = wid >> 1, wn = wid & 1;
  const int l15  = lane & 15;
  const int lhi  = lane >> 4;
  const int bm   = blockIdx.x * 128;
  const int bn   = blockIdx.y * 64;

  f32x4 acc[4][2];
#pragma unroll
  for (int i = 0; i < 4; i++)
#pragma unroll
    for (int j = 0; j < 2; j++) acc[i][j] = (f32x4){0.f, 0.f, 0.f, 0.f};

  const int lrow  = lane >> 3;
  const int gcol8 = lane & 7;

#define OPROJ_STAGE(buf, k0)                                                      \
  {                                                                               \
    _Pragma("unroll")                                                             \
    for (int c = 0; c < 4; c++) {                                                 \
      const int row  = c * 32 + wid * 8 + lrow;                                   \
      const int scol = (gcol8 ^ (row & 7)) * 8;                                   \
      gll16(X + (size_t)(bm + row) * HID + (k0) + scol,                           \
            (char*)&As[buf][0] + c * 4096 + wid * 1024);                          \
      if (c < 2)                                                                  \
        gll16(W + (size_t)(bn + row) * HID + (k0) + scol,                         \
              (char*)&Bs[buf][0] + c * 4096 + wid * 1024);                        \
    }                                                                             \
  }

  OPROJ_STAGE(0, 0);
  for (int t = 0; t < 16; t++) {
    __syncthreads();
    if (t < 15) OPROJ_STAGE((t + 1) & 1, (t + 1) * 64);
    const u16* A = &As[t & 1][0];
    const u16* B = &Bs[t & 1][0];
#pragma unroll
    for (int ks = 0; ks < 2; ks++) {
      bf16x8 af[4], bfm[2];
#pragma unroll
      for (int i = 0; i < 4; i++) {
        const int row = wm * 64 + i * 16 + l15;
        af[i] = *(const bf16x8*)&A[row * 64 + swz(row, ks * 32 + lhi * 8)];
      }
#pragma unroll
      for (int j = 0; j < 2; j++) {
        const int row = wn * 32 + j * 16 + l15;
        bfm[j] = *(const bf16x8*)&B[row * 64 + swz(row, ks * 32 + lhi * 8)];
      }
#pragma unroll
      for (int i = 0; i < 4; i++)
#pragma unroll
        for (int j = 0; j < 2; j++)
          acc[i][j] = __builtin_amdgcn_mfma_f32_16x16x32_bf16(af[i], bfm[j], acc[i][j], 0, 0, 0);
    }
  }
#undef OPROJ_STAGE

#pragma unroll
  for (int j = 0; j < 2; j++) {
    const int n = bn + wn * 32 + j * 16 + l15;
    const float bv_ = bias[n];
#pragma unroll
    for (int i = 0; i < 4; i++)
#pragma unroll
      for (int r = 0; r < 4; r++) {
        const int m = bm + wm * 64 + i * 16 + lhi * 4 + r;
        Out[(size_t)m * HID + n] = acc[i][j][r] + bv_;
      }
  }
}

// ---------------- launch ------------------------------------------------------
extern "C" void kernel_launch(void* const* d_in, const int* in_sizes, int n_in,
                              void* d_out, int out_size, void* d_ws, size_t ws_size,
                              hipStream_t stream) {
  const float* q  = (const float*)d_in[0];
  const float* k  = (const float*)d_in[1];
  const float* v  = (const float*)d_in[2];
  const float* Wq = (const float*)d_in[3];
  const float* bq = (const float*)d_in[4];
  const float* Wk = (const float*)d_in[5];
  const float* bk = (const float*)d_in[6];
  const float* Wv = (const float*)d_in[7];
  const float* bv = (const float*)d_in[8];
  const float* Wo = (const float*)d_in[9];
  const float* bo = (const float*)d_in[10];

  u16* ws   = (u16*)d_ws;
  u16* wqkv = ws;                     // Wq,Wk,Wv bf16 @ 0,1M,2M
  u16* wob  = ws + 3u * MEG;          // Wo bf16
  u16* qb   = ws + 4u * MEG;          // q bf16; reused as Ab after proj
  u16* Qb   = ws + 8u * MEG;          // [B,H,S,D]
  u16* Kb   = ws + 12u * MEG;         // [B,H,S,D]
  u16* Vtb  = ws + 16u * MEG;         // [B,H,D,S]
  u16* Ab   = qb;
  u16* kbf  = (u16*)d_out;            // k bf16 in d_out scratch
  u16* vbf  = (u16*)d_out + 4u * MEG; // v bf16

  cvt_kernel<<<dim3(1024, 16), 256, 0, stream>>>(Wq, Wk, Wv, Wo, q, k, v, ws, kbf);

  proj_kernel<<<dim3(32, 8, 3), 256, 0, stream>>>(qb, kbf, vbf, wqkv, bq, bk, bv,
                                                  Qb, Kb, Vtb);

  attn_kernel<<<dim3(1024), 512, 0, stream>>>(Qb, Kb, Vtb, Ab);

  oproj_kernel<<<dim3(32, 16), 256, 0, stream>>>(Ab, wob, bo, (float*)d_out);
}

// Round 5
// 127.778 us; speedup vs baseline: 2.5633x; 1.0752x over previous
//
#include <hip/hip_runtime.h>
#include <hip/hip_bf16.h>

// MHA forward, MI355X gfx950.
// cvt (weights+activations -> bf16) -> batched QKV proj GEMM (2-phase dbuf,
// swizzled LDS, global_load_lds) -> causal flash attn (swapped-QK in-register
// softmax, T14 reg-prefetch issue-early/write-late, XCD remap) -> out GEMM.
// HIDDEN=1024, HEADS=16, HEAD_DIM=64, B=2, S=2048.

typedef __attribute__((ext_vector_type(4))) float f32x4;
typedef __attribute__((ext_vector_type(8))) short bf16x8;
typedef unsigned short u16;

#define SEQ   2048
#define NH    16
#define HD    64
#define HID   1024
#define CEXP  0.1803368801f  // 0.125 * log2(e)
#define MEG   1048576u

static __device__ __forceinline__ u16 f2bf(float f) {
  union { float f; unsigned int u; } x; x.f = f;
  unsigned int r = x.u + 0x7fffu + ((x.u >> 16) & 1u);  // RNE
  return (u16)(r >> 16);
}

// XOR swizzle on 8-elem bf16 chunks within a 64-elem row (T2, G4).
static __device__ __forceinline__ int swz(int row, int col8) {
  return col8 ^ ((row & 7) << 3);
}

// async global->LDS, 16B/lane; lds dest wave-uniform base (guide §5).
static __device__ __forceinline__ void gll16(const void* g, void* l) {
  __builtin_amdgcn_global_load_lds(
      (const __attribute__((address_space(1))) void*)g,
      (__attribute__((address_space(3))) void*)l, 16, 0, 0);
}

// ---------------- f32 -> bf16 conversion: 16 x 1M-elem slices ----------------
__global__ __launch_bounds__(256) void cvt_kernel(
    const float* __restrict__ Wq, const float* __restrict__ Wk,
    const float* __restrict__ Wv, const float* __restrict__ Wo,
    const float* __restrict__ q, const float* __restrict__ k,
    const float* __restrict__ v,
    u16* __restrict__ wsout, u16* __restrict__ dob) {
  const int y = blockIdx.y;
  const int c = y & 3;
  const float* src;
  u16* dst;
  if (y < 4) {
    src = (y == 0) ? Wq : (y == 1) ? Wk : (y == 2) ? Wv : Wo;
    dst = wsout + (size_t)y * MEG;
  } else if (y < 8) {
    src = q + (size_t)c * MEG;
    dst = wsout + 4u * MEG + (size_t)c * MEG;
  } else if (y < 12) {
    src = k + (size_t)c * MEG;
    dst = dob + (size_t)c * MEG;
  } else {
    src = v + (size_t)c * MEG;
    dst = dob + 4u * MEG + (size_t)c * MEG;
  }
  int i = (blockIdx.x * 256 + threadIdx.x) * 4;
  float4 f = *(const float4*)(src + i);
  ushort4 o;
  o.x = f2bf(f.x); o.y = f2bf(f.y); o.z = f2bf(f.z); o.w = f2bf(f.w);
  *(ushort4*)(dst + i) = o;
}

// -------- batched QKV projection: C = X @ W^T + b, scatter to heads ----------
// z=0: Q -> [B,H,S,D]; z=1: K -> [B,H,S,D]; z=2: V -> [B,H,D,S] (transposed).
// 128x128 tile, BK=64, 2-phase double-buffered gll staging, swizzled LDS.
__global__ __launch_bounds__(256) void proj_kernel(
    const u16* __restrict__ Xq, const u16* __restrict__ Xk,
    const u16* __restrict__ Xv, const u16* __restrict__ Wc,
    const float* __restrict__ bq, const float* __restrict__ bk,
    const float* __restrict__ bvp,
    u16* __restrict__ Qo, u16* __restrict__ Ko, u16* __restrict__ Vto) {
  __shared__ u16 As[2][128 * 64];
  __shared__ u16 Bs[2][128 * 64];

  const int tid  = threadIdx.x;
  const int lane = tid & 63;
  const int wid  = tid >> 6;
  const int wm   = wid >> 1, wn = wid & 1;
  const int l15  = lane & 15;
  const int lhi  = lane >> 4;
  const int z    = blockIdx.z;
  const int bm   = blockIdx.x * 128;
  const int bn   = blockIdx.y * 128;

  const u16* X = (z == 0) ? Xq : (z == 1) ? Xk : Xv;
  const u16* W = Wc + (size_t)z * (HID * HID);
  const float* bias = (z == 0) ? bq : (z == 1) ? bk : bvp;

  f32x4 acc[4][4];
#pragma unroll
  for (int i = 0; i < 4; i++)
#pragma unroll
    for (int j = 0; j < 4; j++) acc[i][j] = (f32x4){0.f, 0.f, 0.f, 0.f};

  const int lrow  = lane >> 3;      // 0..7
  const int gcol8 = lane & 7;       // 8-elem chunk index

#define PROJ_STAGE(buf, k0)                                                       \
  {                                                                               \
    _Pragma("unroll")                                                             \
    for (int c = 0; c < 4; c++) {                                                 \
      const int row  = c * 32 + wid * 8 + lrow;                                   \
      const int scol = (gcol8 ^ (row & 7)) * 8; /* inverse-swizzled source */     \
      gll16(X + (size_t)(bm + row) * HID + (k0) + scol,                           \
            (char*)&As[buf][0] + c * 4096 + wid * 1024);                          \
      gll16(W + (size_t)(bn + row) * HID + (k0) + scol,                           \
            (char*)&Bs[buf][0] + c * 4096 + wid * 1024);                          \
    }                                                                             \
  }

  PROJ_STAGE(0, 0);
  for (int t = 0; t < 16; t++) {
    __syncthreads();  // drains vmcnt for buf[t&1]; prior reads of buf[(t+1)&1] done
    if (t < 15) PROJ_STAGE((t + 1) & 1, (t + 1) * 64);
    const u16* A = &As[t & 1][0];
    const u16* B = &Bs[t & 1][0];
#pragma unroll
    for (int ks = 0; ks < 2; ks++) {
      bf16x8 af[4], bfm[4];
#pragma unroll
      for (int i = 0; i < 4; i++) {
        const int row = wm * 64 + i * 16 + l15;
        af[i] = *(const bf16x8*)&A[row * 64 + swz(row, ks * 32 + lhi * 8)];
      }
#pragma unroll
      for (int j = 0; j < 4; j++) {
        const int row = wn * 64 + j * 16 + l15;
        bfm[j] = *(const bf16x8*)&B[row * 64 + swz(row, ks * 32 + lhi * 8)];
      }
#pragma unroll
      for (int i = 0; i < 4; i++)
#pragma unroll
        for (int j = 0; j < 4; j++)
          acc[i][j] = __builtin_amdgcn_mfma_f32_16x16x32_bf16(af[i], bfm[j], acc[i][j], 0, 0, 0);
    }
  }

  // epilogue: bias + scatter to heads
  const int bb = bm >> 11;  // tile never crosses batch
#pragma unroll
  for (int j = 0; j < 4; j++) {
    const int n = bn + wn * 64 + j * 16 + l15;
    const float bv_ = bias[n];
    const int h = n >> 6, d = n & 63;
    if (z == 2) {
#pragma unroll
      for (int i = 0; i < 4; i++) {
        const int s0 = (bm + wm * 64 + i * 16 + lhi * 4) & 2047;
        ushort4 t;
        t.x = f2bf(acc[i][j][0] + bv_);
        t.y = f2bf(acc[i][j][1] + bv_);
        t.z = f2bf(acc[i][j][2] + bv_);
        t.w = f2bf(acc[i][j][3] + bv_);
        *(ushort4*)&Vto[((size_t)(bb * NH + h) * HD + d) * SEQ + s0] = t;
      }
    } else {
      u16* O = z ? Ko : Qo;
#pragma unroll
      for (int i = 0; i < 4; i++)
#pragma unroll
        for (int r = 0; r < 4; r++) {
          const int m = bm + wm * 64 + i * 16 + lhi * 4 + r;
          const int s = m & 2047;
          O[(((size_t)(bb * NH + h) * SEQ + s) << 6) + d] = f2bf(acc[i][j][r] + bv_);
        }
    }
  }
#undef PROJ_STAGE
}

// ---------------- causal flash attention -------------------------------------
// Q,K: bf16 [B,H,S,D]; Vt: bf16 [B,H,D,S]; out: bf16 [B,S,H*D].
// 512 thr = 2 k-groups x 4 row-waves; swapped QK^T (lane = one q-row).
// T14: next tile loaded global->reg before compute, reg->LDS after barrier.
__global__ __launch_bounds__(512) void attn_kernel(
    const u16* __restrict__ Q, const u16* __restrict__ K,
    const u16* __restrict__ Vt, u16* __restrict__ Aout) {
  // K[g] @ g*8192, V[g] @ 16384+g*8192 ([64][64] swizzled),
  // Psh[w] @ 32768+wid*2304 ([16][72]). total 51200 B -> 3 blocks/CU.
  __shared__ __align__(16) char pool[51200];

  const int tid  = threadIdx.x;
  const int lane = tid & 63;
  const int wid  = tid >> 6;
  const int rw   = wid & 3;
  const int g    = wid >> 2;
  const int l15  = lane & 15;
  const int lhi  = lane >> 4;

  // XCD-locality remap (T1)
  const int flat = blockIdx.x;
  const int slot = flat >> 3;
  const int bh   = (flat & 7) * 4 + (slot & 3);
  const int qt   = slot >> 2;
  const int b    = bh >> 4, h = bh & 15;
  const size_t base = (size_t)bh * SEQ * HD;

  u16* Ksh = (u16*)(pool + g * 8192);
  u16* Vsh = (u16*)(pool + 16384 + g * 8192);
  u16* Psh = (u16*)(pool + 32768 + wid * 2304);

  const int qrow = qt * 64 + rw * 16 + l15;
  bf16x8 aq[2];
  aq[0] = *(const bf16x8*)&Q[base + (size_t)qrow * HD + lhi * 8];
  aq[1] = *(const bf16x8*)&Q[base + (size_t)qrow * HD + 32 + lhi * 8];

  f32x4 o[4];
#pragma unroll
  for (int n = 0; n < 4; n++) o[n] = (f32x4){0.f, 0.f, 0.f, 0.f};
  float m_s = -1e30f, l_s = 0.f;

  // staging mapping: 256 thr/group; row 0..63, 16-col chunk
  const int gt   = tid & 255;
  const int srow = gt >> 2;
  const int sd   = (gt & 3) * 16;

  bf16x8 pk0, pk1, pv0, pv1;  // prefetched next-tile K/V (T14)

#define ATTN_LOAD(kt_)                                                            \
  {                                                                               \
    const u16* kp = K + base + (size_t)((kt_) * 64 + srow) * HD + sd;             \
    pk0 = *(const bf16x8*)kp;                                                     \
    pk1 = *(const bf16x8*)(kp + 8);                                               \
    const u16* vp = Vt + base + (size_t)srow * SEQ + (kt_) * 64 + sd;             \
    pv0 = *(const bf16x8*)vp;                                                     \
    pv1 = *(const bf16x8*)(vp + 8);                                               \
  }

  if (g <= qt) ATTN_LOAD(g);

  const int nsteps = qt / 2 + 1;
  for (int it = 0; it < nsteps; ++it) {
    const int kt = 2 * it + g;
    const bool act = (kt <= qt);
    __syncthreads();  // prior tile's LDS reads done
    if (act) {        // write prefetched tile into LDS (swizzled both sides)
      *(bf16x8*)&Ksh[srow * 64 + swz(srow, sd)]     = pk0;
      *(bf16x8*)&Ksh[srow * 64 + swz(srow, sd + 8)] = pk1;
      *(bf16x8*)&Vsh[srow * 64 + swz(srow, sd)]     = pv0;
      *(bf16x8*)&Vsh[srow * 64 + swz(srow, sd + 8)] = pv1;
    }
    const int ktn = kt + 2;
    if (ktn <= qt) ATTN_LOAD(ktn);  // issue-early: lands during compute
    __syncthreads();  // LDS writes visible
    if (act) {
      // S^T = mfma(K, Q): lane l15 = q-row; regs hold k = kt*64 + n*16 + lhi*4 + r
      f32x4 sc[4];
#pragma unroll
      for (int n = 0; n < 4; n++) {
        sc[n] = (f32x4){0.f, 0.f, 0.f, 0.f};
#pragma unroll
        for (int ks = 0; ks < 2; ks++) {
          const int krow = n * 16 + l15;
          bf16x8 bk = *(const bf16x8*)&Ksh[krow * 64 + swz(krow, ks * 32 + lhi * 8)];
          sc[n] = __builtin_amdgcn_mfma_f32_16x16x32_bf16(bk, aq[ks], sc[n], 0, 0, 0);
        }
      }
      if (kt == qt) {  // causal mask on diagonal tile
#pragma unroll
        for (int n = 0; n < 4; n++)
#pragma unroll
          for (int r = 0; r < 4; r++)
            if (kt * 64 + n * 16 + lhi * 4 + r > qrow) sc[n][r] = -1e30f;
      }
      // in-register online softmax
      float mx = -1e30f;
#pragma unroll
      for (int n = 0; n < 4; n++)
#pragma unroll
        for (int r = 0; r < 4; r++) mx = fmaxf(mx, sc[n][r]);
      mx = fmaxf(mx, __shfl_xor(mx, 16, 64));
      mx = fmaxf(mx, __shfl_xor(mx, 32, 64));
      const float mnew = fmaxf(m_s, mx);
      const float fac = __builtin_amdgcn_exp2f((m_s - mnew) * CEXP);
      float ps = 0.f;
      u16 pb[4][4];
#pragma unroll
      for (int n = 0; n < 4; n++)
#pragma unroll
        for (int r = 0; r < 4; r++) {
          const float e = __builtin_amdgcn_exp2f((sc[n][r] - mnew) * CEXP);
          ps += e;
          pb[n][r] = f2bf(e);
        }
      ps += __shfl_xor(ps, 16, 64);
      ps += __shfl_xor(ps, 32, 64);
      l_s = l_s * fac + ps;
      m_s = mnew;
      float facr[4];
#pragma unroll
      for (int r = 0; r < 4; r++) facr[r] = __shfl(fac, lhi * 4 + r, 64);
#pragma unroll
      for (int n = 0; n < 4; n++) {
        o[n][0] *= facr[0]; o[n][1] *= facr[1];
        o[n][2] *= facr[2]; o[n][3] *= facr[3];
      }
      // P -> per-wave LDS -> A-frag
#pragma unroll
      for (int n = 0; n < 4; n++) {
        ushort4 t; t.x = pb[n][0]; t.y = pb[n][1]; t.z = pb[n][2]; t.w = pb[n][3];
        *(ushort4*)&Psh[l15 * 72 + n * 16 + lhi * 4] = t;
      }
      bf16x8 ap0 = *(const bf16x8*)&Psh[l15 * 72 + lhi * 8];
      bf16x8 ap1 = *(const bf16x8*)&Psh[l15 * 72 + 32 + lhi * 8];
#pragma unroll
      for (int n = 0; n < 4; n++) {
        const int vrow = n * 16 + l15;
        bf16x8 bv0 = *(const bf16x8*)&Vsh[vrow * 64 + swz(vrow, lhi * 8)];
        bf16x8 bv1 = *(const bf16x8*)&Vsh[vrow * 64 + swz(vrow, 32 + lhi * 8)];
        o[n] = __builtin_amdgcn_mfma_f32_16x16x32_bf16(ap0, bv0, o[n], 0, 0, 0);
        o[n] = __builtin_amdgcn_mfma_f32_16x16x32_bf16(ap1, bv1, o[n], 0, 0, 0);
      }
    }
  }
#undef ATTN_LOAD

  __syncthreads();
  float m_o[4], l_o[4];
#pragma unroll
  for (int r = 0; r < 4; r++) {
    m_o[r] = __shfl(m_s, lhi * 4 + r, 64);
    l_o[r] = __shfl(l_s, lhi * 4 + r, 64);
  }

  // merge the two k-groups' partials (pool reused; K/V/P dead)
  f32x4* comb = (f32x4*)pool;
  const int ci = (rw * 64 + lane) * 6;
  if (g == 0) {
#pragma unroll
    for (int n = 0; n < 4; n++) comb[ci + n] = o[n];
    comb[ci + 4] = (f32x4){m_o[0], m_o[1], m_o[2], m_o[3]};
    comb[ci + 5] = (f32x4){l_o[0], l_o[1], l_o[2], l_o[3]};
  }
  __syncthreads();
  if (g == 1) {
    f32x4 m0 = comb[ci + 4];
    f32x4 l0 = comb[ci + 5];
    float a0[4], a1[4], inv[4];
#pragma unroll
    for (int r = 0; r < 4; r++) {
      const float m = fmaxf(m0[r], m_o[r]);
      a0[r] = __builtin_amdgcn_exp2f((m0[r] - m) * CEXP);
      a1[r] = __builtin_amdgcn_exp2f((m_o[r] - m) * CEXP);
      inv[r] = 1.0f / (l0[r] * a0[r] + l_o[r] * a1[r]);
    }
#pragma unroll
    for (int n = 0; n < 4; n++) {
      f32x4 o0 = comb[ci + n];
#pragma unroll
      for (int r = 0; r < 4; r++) {
        const int rowg = qt * 64 + rw * 16 + lhi * 4 + r;
        const float val = (o0[r] * a0[r] + o[n][r] * a1[r]) * inv[r];
        Aout[(((size_t)(b * SEQ + rowg)) << 10) + h * 64 + n * 16 + l15] = f2bf(val);
      }
    }
  }
}

// ---------------- out projection: f32 out = Ab @ Wo^T + bo -------------------
// 128x64 tile, BK=64, 2-phase dbuf, swizzled. grid (32,16) = 2/CU.
__global__ __launch_bounds__(256) void oproj_kernel(
    const u16* __restrict__ X, const u16* __restrict__ W,
    const float* __restrict__ bias, float* __restrict__ Out) {
  __shared__ u16 As[2][128 * 64];
  __shared__ u16 Bs[2][64 * 64];

  const int tid  = threadIdx.x;
  const int lane = tid & 63;
  const int wid  = tid >> 6;
  const int wm   = wid >> 1, wn = wid & 1;
  const int l15  = lane & 15;
  const int lhi  = lane >> 4;
  const int bm   = blockIdx.x * 128;
  const int bn   = blockIdx.y * 64;

  f32x4 acc[4][2];
#pragma unroll
  for (int i = 0; i < 4; i++)
#pragma unroll
    for (int j = 0; j < 2; j++) acc[i][j] = (f32x4){0.f, 0.f, 0.f, 0.f};

  const int lrow  = lane >> 3;
  const int gcol8 = lane & 7;

#define OPROJ_STAGE(buf, k0)                                                      \
  {                                                                               \
    _Pragma("unroll")                                                             \
    for (int c = 0; c < 4; c++) {                                                 \
      const int row  = c * 32 + wid * 8 + lrow;                                   \
      const int scol = (gcol8 ^ (row & 7)) * 8;                                   \
      gll16(X + (size_t)(bm + row) * HID + (k0) + scol,                           \
            (char*)&As[buf][0] + c * 4096 + wid * 1024);                          \
      if (c < 2)                                                                  \
        gll16(W + (size_t)(bn + row) * HID + (k0) + scol,                         \
              (char*)&Bs[buf][0] + c * 4096 + wid * 1024);                        \
    }                                                                             \
  }

  OPROJ_STAGE(0, 0);
  for (int t = 0; t < 16; t++) {
    __syncthreads();
    if (t < 15) OPROJ_STAGE((t + 1) & 1, (t + 1) * 64);
    const u16* A = &As[t & 1][0];
    const u16* B = &Bs[t & 1][0];
#pragma unroll
    for (int ks = 0; ks < 2; ks++) {
      bf16x8 af[4], bfm[2];
#pragma unroll
      for (int i = 0; i < 4; i++) {
        const int row = wm * 64 + i * 16 + l15;
        af[i] = *(const bf16x8*)&A[row * 64 + swz(row, ks * 32 + lhi * 8)];
      }
#pragma unroll
      for (int j = 0; j < 2; j++) {
        const int row = wn * 32 + j * 16 + l15;
        bfm[j] = *(const bf16x8*)&B[row * 64 + swz(row, ks * 32 + lhi * 8)];
      }
#pragma unroll
      for (int i = 0; i < 4; i++)
#pragma unroll
        for (int j = 0; j < 2; j++)
          acc[i][j] = __builtin_amdgcn_mfma_f32_16x16x32_bf16(af[i], bfm[j], acc[i][j], 0, 0, 0);
    }
  }
#undef OPROJ_STAGE

#pragma unroll
  for (int j = 0; j < 2; j++) {
    const int n = bn + wn * 32 + j * 16 + l15;
    const float bv_ = bias[n];
#pragma unroll
    for (int i = 0; i < 4; i++)
#pragma unroll
      for (int r = 0; r < 4; r++) {
        const int m = bm + wm * 64 + i * 16 + lhi * 4 + r;
        Out[(size_t)m * HID + n] = acc[i][j][r] + bv_;
      }
  }
}

// ---------------- launch ------------------------------------------------------
extern "C" void kernel_launch(void* const* d_in, const int* in_sizes, int n_in,
                              void* d_out, int out_size, void* d_ws, size_t ws_size,
                              hipStream_t stream) {
  const float* q  = (const float*)d_in[0];
  const float* k  = (const float*)d_in[1];
  const float* v  = (const float*)d_in[2];
  const float* Wq = (const float*)d_in[3];
  const float* bq = (const float*)d_in[4];
  const float* Wk = (const float*)d_in[5];
  const float* bk = (const float*)d_in[6];
  const float* Wv = (const float*)d_in[7];
  const float* bv = (const float*)d_in[8];
  const float* Wo = (const float*)d_in[9];
  const float* bo = (const float*)d_in[10];

  u16* ws   = (u16*)d_ws;
  u16* wqkv = ws;                     // Wq,Wk,Wv bf16 @ 0,1M,2M
  u16* wob  = ws + 3u * MEG;          // Wo bf16
  u16* qb   = ws + 4u * MEG;          // q bf16; reused as Ab after proj
  u16* Qb   = ws + 8u * MEG;          // [B,H,S,D]
  u16* Kb   = ws + 12u * MEG;         // [B,H,S,D]
  u16* Vtb  = ws + 16u * MEG;         // [B,H,D,S]
  u16* Ab   = qb;
  u16* kbf  = (u16*)d_out;            // k bf16 in d_out scratch
  u16* vbf  = (u16*)d_out + 4u * MEG; // v bf16

  cvt_kernel<<<dim3(1024, 16), 256, 0, stream>>>(Wq, Wk, Wv, Wo, q, k, v, ws, kbf);

  proj_kernel<<<dim3(32, 8, 3), 256, 0, stream>>>(qb, kbf, vbf, wqkv, bq, bk, bv,
                                                  Qb, Kb, Vtb);

  attn_kernel<<<dim3(1024), 512, 0, stream>>>(Qb, Kb, Vtb, Ab);

  oproj_kernel<<<dim3(32, 16), 256, 0, stream>>>(Ab, wob, bo, (float*)d_out);
}

// Round 6
// 119.645 us; speedup vs baseline: 2.7376x; 1.0680x over previous
//
#include <hip/hip_runtime.h>
#include <hip/hip_bf16.h>

// MHA forward, MI355X gfx950.
// cvt (weights+activations -> bf16) -> batched QKV proj GEMM (2-phase dbuf,
// swizzled LDS, global_load_lds) -> causal flash attn (swapped-QK in-register
// softmax + T13 defer-max + HW bf16 cvt + T5 setprio, T14 reg-prefetch,
// XCD remap + LPT order) -> out GEMM.
// HIDDEN=1024, HEADS=16, HEAD_DIM=64, B=2, S=2048.

typedef __attribute__((ext_vector_type(4))) float f32x4;
typedef __attribute__((ext_vector_type(8))) short bf16x8;
typedef unsigned short u16;

#define SEQ   2048
#define NH    16
#define HD    64
#define HID   1024
#define CEXP  0.1803368801f  // 0.125 * log2(e)
#define MEG   1048576u

// HW round-to-nearest-even f32->bf16 (compiler emits v_cvt_pk_bf16_f32 pairs).
static __device__ __forceinline__ u16 f2bf(float f) {
  union { __hip_bfloat16 h; u16 u; } c;
  c.h = __float2bfloat16(f);
  return c.u;
}

// XOR swizzle on 8-elem bf16 chunks within a 64-elem row (T2, G4).
static __device__ __forceinline__ int swz(int row, int col8) {
  return col8 ^ ((row & 7) << 3);
}

// async global->LDS, 16B/lane; lds dest wave-uniform base (guide §5).
static __device__ __forceinline__ void gll16(const void* g, void* l) {
  __builtin_amdgcn_global_load_lds(
      (const __attribute__((address_space(1))) void*)g,
      (__attribute__((address_space(3))) void*)l, 16, 0, 0);
}

// ---------------- f32 -> bf16 conversion: 16 x 1M-elem slices ----------------
__global__ __launch_bounds__(256) void cvt_kernel(
    const float* __restrict__ Wq, const float* __restrict__ Wk,
    const float* __restrict__ Wv, const float* __restrict__ Wo,
    const float* __restrict__ q, const float* __restrict__ k,
    const float* __restrict__ v,
    u16* __restrict__ wsout, u16* __restrict__ dob) {
  const int y = blockIdx.y;
  const int c = y & 3;
  const float* src;
  u16* dst;
  if (y < 4) {
    src = (y == 0) ? Wq : (y == 1) ? Wk : (y == 2) ? Wv : Wo;
    dst = wsout + (size_t)y * MEG;
  } else if (y < 8) {
    src = q + (size_t)c * MEG;
    dst = wsout + 4u * MEG + (size_t)c * MEG;
  } else if (y < 12) {
    src = k + (size_t)c * MEG;
    dst = dob + (size_t)c * MEG;
  } else {
    src = v + (size_t)c * MEG;
    dst = dob + 4u * MEG + (size_t)c * MEG;
  }
  int i = (blockIdx.x * 256 + threadIdx.x) * 4;
  float4 f = *(const float4*)(src + i);
  ushort4 o;
  o.x = f2bf(f.x); o.y = f2bf(f.y); o.z = f2bf(f.z); o.w = f2bf(f.w);
  *(ushort4*)(dst + i) = o;
}

// -------- batched QKV projection: C = X @ W^T + b, scatter to heads ----------
// z=0: Q -> [B,H,S,D]; z=1: K -> [B,H,S,D]; z=2: V -> [B,H,D,S] (transposed).
// 128x128 tile, BK=64, 2-phase double-buffered gll staging, swizzled LDS.
__global__ __launch_bounds__(256) void proj_kernel(
    const u16* __restrict__ Xq, const u16* __restrict__ Xk,
    const u16* __restrict__ Xv, const u16* __restrict__ Wc,
    const float* __restrict__ bq, const float* __restrict__ bk,
    const float* __restrict__ bvp,
    u16* __restrict__ Qo, u16* __restrict__ Ko, u16* __restrict__ Vto) {
  __shared__ u16 As[2][128 * 64];
  __shared__ u16 Bs[2][128 * 64];

  const int tid  = threadIdx.x;
  const int lane = tid & 63;
  const int wid  = tid >> 6;
  const int wm   = wid >> 1, wn = wid & 1;
  const int l15  = lane & 15;
  const int lhi  = lane >> 4;
  const int z    = blockIdx.z;
  const int bm   = blockIdx.x * 128;
  const int bn   = blockIdx.y * 128;

  const u16* X = (z == 0) ? Xq : (z == 1) ? Xk : Xv;
  const u16* W = Wc + (size_t)z * (HID * HID);
  const float* bias = (z == 0) ? bq : (z == 1) ? bk : bvp;

  f32x4 acc[4][4];
#pragma unroll
  for (int i = 0; i < 4; i++)
#pragma unroll
    for (int j = 0; j < 4; j++) acc[i][j] = (f32x4){0.f, 0.f, 0.f, 0.f};

  const int lrow  = lane >> 3;      // 0..7
  const int gcol8 = lane & 7;       // 8-elem chunk index

#define PROJ_STAGE(buf, k0)                                                       \
  {                                                                               \
    _Pragma("unroll")                                                             \
    for (int c = 0; c < 4; c++) {                                                 \
      const int row  = c * 32 + wid * 8 + lrow;                                   \
      const int scol = (gcol8 ^ (row & 7)) * 8; /* inverse-swizzled source */     \
      gll16(X + (size_t)(bm + row) * HID + (k0) + scol,                           \
            (char*)&As[buf][0] + c * 4096 + wid * 1024);                          \
      gll16(W + (size_t)(bn + row) * HID + (k0) + scol,                           \
            (char*)&Bs[buf][0] + c * 4096 + wid * 1024);                          \
    }                                                                             \
  }

  PROJ_STAGE(0, 0);
  for (int t = 0; t < 16; t++) {
    __syncthreads();  // drains vmcnt for buf[t&1]; prior reads of buf[(t+1)&1] done
    if (t < 15) PROJ_STAGE((t + 1) & 1, (t + 1) * 64);
    const u16* A = &As[t & 1][0];
    const u16* B = &Bs[t & 1][0];
#pragma unroll
    for (int ks = 0; ks < 2; ks++) {
      bf16x8 af[4], bfm[4];
#pragma unroll
      for (int i = 0; i < 4; i++) {
        const int row = wm * 64 + i * 16 + l15;
        af[i] = *(const bf16x8*)&A[row * 64 + swz(row, ks * 32 + lhi * 8)];
      }
#pragma unroll
      for (int j = 0; j < 4; j++) {
        const int row = wn * 64 + j * 16 + l15;
        bfm[j] = *(const bf16x8*)&B[row * 64 + swz(row, ks * 32 + lhi * 8)];
      }
#pragma unroll
      for (int i = 0; i < 4; i++)
#pragma unroll
        for (int j = 0; j < 4; j++)
          acc[i][j] = __builtin_amdgcn_mfma_f32_16x16x32_bf16(af[i], bfm[j], acc[i][j], 0, 0, 0);
    }
  }

  // epilogue: bias + scatter to heads
  const int bb = bm >> 11;  // tile never crosses batch
#pragma unroll
  for (int j = 0; j < 4; j++) {
    const int n = bn + wn * 64 + j * 16 + l15;
    const float bv_ = bias[n];
    const int h = n >> 6, d = n & 63;
    if (z == 2) {
#pragma unroll
      for (int i = 0; i < 4; i++) {
        const int s0 = (bm + wm * 64 + i * 16 + lhi * 4) & 2047;
        ushort4 t;
        t.x = f2bf(acc[i][j][0] + bv_);
        t.y = f2bf(acc[i][j][1] + bv_);
        t.z = f2bf(acc[i][j][2] + bv_);
        t.w = f2bf(acc[i][j][3] + bv_);
        *(ushort4*)&Vto[((size_t)(bb * NH + h) * HD + d) * SEQ + s0] = t;
      }
    } else {
      u16* O = z ? Ko : Qo;
#pragma unroll
      for (int i = 0; i < 4; i++)
#pragma unroll
        for (int r = 0; r < 4; r++) {
          const int m = bm + wm * 64 + i * 16 + lhi * 4 + r;
          const int s = m & 2047;
          O[(((size_t)(bb * NH + h) * SEQ + s) << 6) + d] = f2bf(acc[i][j][r] + bv_);
        }
    }
  }
#undef PROJ_STAGE
}

// ---------------- causal flash attention -------------------------------------
// Q,K: bf16 [B,H,S,D]; Vt: bf16 [B,H,D,S]; out: bf16 [B,S,H*D].
// 512 thr = 2 k-groups x 4 row-waves; swapped QK^T (lane = one q-row).
// T14 issue-early/write-late staging; T13 defer-max; T5 setprio.
__global__ __launch_bounds__(512) void attn_kernel(
    const u16* __restrict__ Q, const u16* __restrict__ K,
    const u16* __restrict__ Vt, u16* __restrict__ Aout) {
  // K[g] @ g*8192, V[g] @ 16384+g*8192 ([64][64] swizzled),
  // Psh[w] @ 32768+wid*2304 ([16][72]). total 51200 B -> 3 blocks/CU.
  __shared__ __align__(16) char pool[51200];

  const int tid  = threadIdx.x;
  const int lane = tid & 63;
  const int wid  = tid >> 6;
  const int rw   = wid & 3;
  const int g    = wid >> 2;
  const int l15  = lane & 15;
  const int lhi  = lane >> 4;

  // XCD-locality remap (T1) + LPT: longest q-tiles first.
  const int flat = blockIdx.x;
  const int slot = flat >> 3;
  const int bh   = (flat & 7) * 4 + (slot & 3);
  const int qt   = 31 - (slot >> 2);
  const int b    = bh >> 4, h = bh & 15;
  const size_t base = (size_t)bh * SEQ * HD;

  u16* Ksh = (u16*)(pool + g * 8192);
  u16* Vsh = (u16*)(pool + 16384 + g * 8192);
  u16* Psh = (u16*)(pool + 32768 + wid * 2304);

  const int qrow = qt * 64 + rw * 16 + l15;
  bf16x8 aq[2];
  aq[0] = *(const bf16x8*)&Q[base + (size_t)qrow * HD + lhi * 8];
  aq[1] = *(const bf16x8*)&Q[base + (size_t)qrow * HD + 32 + lhi * 8];

  f32x4 o[4];
#pragma unroll
  for (int n = 0; n < 4; n++) o[n] = (f32x4){0.f, 0.f, 0.f, 0.f};
  float m_s = -1e30f, l_s = 0.f;

  // staging mapping: 256 thr/group; row 0..63, 16-col chunk
  const int gt   = tid & 255;
  const int srow = gt >> 2;
  const int sd   = (gt & 3) * 16;

  bf16x8 pk0, pk1, pv0, pv1;  // prefetched next-tile K/V (T14)

#define ATTN_LOAD(kt_)                                                            \
  {                                                                               \
    const u16* kp = K + base + (size_t)((kt_) * 64 + srow) * HD + sd;             \
    pk0 = *(const bf16x8*)kp;                                                     \
    pk1 = *(const bf16x8*)(kp + 8);                                               \
    const u16* vp = Vt + base + (size_t)srow * SEQ + (kt_) * 64 + sd;             \
    pv0 = *(const bf16x8*)vp;                                                     \
    pv1 = *(const bf16x8*)(vp + 8);                                               \
  }

  if (g <= qt) ATTN_LOAD(g);

  const int nsteps = qt / 2 + 1;
  for (int it = 0; it < nsteps; ++it) {
    const int kt = 2 * it + g;
    const bool act = (kt <= qt);
    __syncthreads();  // prior tile's LDS reads done
    if (act) {        // write prefetched tile into LDS (swizzled both sides)
      *(bf16x8*)&Ksh[srow * 64 + swz(srow, sd)]     = pk0;
      *(bf16x8*)&Ksh[srow * 64 + swz(srow, sd + 8)] = pk1;
      *(bf16x8*)&Vsh[srow * 64 + swz(srow, sd)]     = pv0;
      *(bf16x8*)&Vsh[srow * 64 + swz(srow, sd + 8)] = pv1;
    }
    const int ktn = kt + 2;
    if (ktn <= qt) ATTN_LOAD(ktn);  // issue-early: lands during compute
    __syncthreads();  // LDS writes visible
    if (act) {
      // S^T = mfma(K, Q): lane l15 = q-row; regs hold k = kt*64 + n*16 + lhi*4 + r
      f32x4 sc[4];
      __builtin_amdgcn_s_setprio(1);
#pragma unroll
      for (int n = 0; n < 4; n++) {
        sc[n] = (f32x4){0.f, 0.f, 0.f, 0.f};
#pragma unroll
        for (int ks = 0; ks < 2; ks++) {
          const int krow = n * 16 + l15;
          bf16x8 bk = *(const bf16x8*)&Ksh[krow * 64 + swz(krow, ks * 32 + lhi * 8)];
          sc[n] = __builtin_amdgcn_mfma_f32_16x16x32_bf16(bk, aq[ks], sc[n], 0, 0, 0);
        }
      }
      __builtin_amdgcn_s_setprio(0);
      if (kt == qt) {  // causal mask on diagonal tile
#pragma unroll
        for (int n = 0; n < 4; n++)
#pragma unroll
          for (int r = 0; r < 4; r++)
            if (kt * 64 + n * 16 + lhi * 4 + r > qrow) sc[n][r] = -1e30f;
      }
      // ---- online softmax, defer-max (T13) ----
      float mx = -1e30f;
#pragma unroll
      for (int n = 0; n < 4; n++)
        mx = fmaxf(mx, fmaxf(fmaxf(sc[n][0], sc[n][1]), fmaxf(sc[n][2], sc[n][3])));
      mx = fmaxf(mx, __shfl_xor(mx, 16, 64));
      mx = fmaxf(mx, __shfl_xor(mx, 32, 64));
      if (__any(mx > m_s + 64.0f)) {  // raw-score THR (e^8 P-bound)
        const float mnew = fmaxf(m_s, mx);
        const float fac = __builtin_amdgcn_exp2f((m_s - mnew) * CEXP);
        l_s *= fac;
        m_s = mnew;
        float facr[4];
#pragma unroll
        for (int r = 0; r < 4; r++) facr[r] = __shfl(fac, lhi * 4 + r, 64);
#pragma unroll
        for (int n = 0; n < 4; n++) {
          o[n][0] *= facr[0]; o[n][1] *= facr[1];
          o[n][2] *= facr[2]; o[n][3] *= facr[3];
        }
      }
      const float nmc = -m_s * CEXP;
      float ps = 0.f;
      u16 pb[4][4];
#pragma unroll
      for (int n = 0; n < 4; n++)
#pragma unroll
        for (int r = 0; r < 4; r++) {
          const float e = __builtin_amdgcn_exp2f(fmaf(sc[n][r], CEXP, nmc));
          ps += e;
          pb[n][r] = f2bf(e);
        }
      ps += __shfl_xor(ps, 16, 64);
      ps += __shfl_xor(ps, 32, 64);
      l_s += ps;
      // P -> per-wave LDS -> A-frag
#pragma unroll
      for (int n = 0; n < 4; n++) {
        ushort4 t; t.x = pb[n][0]; t.y = pb[n][1]; t.z = pb[n][2]; t.w = pb[n][3];
        *(ushort4*)&Psh[l15 * 72 + n * 16 + lhi * 4] = t;
      }
      bf16x8 ap0 = *(const bf16x8*)&Psh[l15 * 72 + lhi * 8];
      bf16x8 ap1 = *(const bf16x8*)&Psh[l15 * 72 + 32 + lhi * 8];
      __builtin_amdgcn_s_setprio(1);
#pragma unroll
      for (int n = 0; n < 4; n++) {
        const int vrow = n * 16 + l15;
        bf16x8 bv0 = *(const bf16x8*)&Vsh[vrow * 64 + swz(vrow, lhi * 8)];
        bf16x8 bv1 = *(const bf16x8*)&Vsh[vrow * 64 + swz(vrow, 32 + lhi * 8)];
        o[n] = __builtin_amdgcn_mfma_f32_16x16x32_bf16(ap0, bv0, o[n], 0, 0, 0);
        o[n] = __builtin_amdgcn_mfma_f32_16x16x32_bf16(ap1, bv1, o[n], 0, 0, 0);
      }
      __builtin_amdgcn_s_setprio(0);
    }
  }
#undef ATTN_LOAD

  __syncthreads();
  float m_o[4], l_o[4];
#pragma unroll
  for (int r = 0; r < 4; r++) {
    m_o[r] = __shfl(m_s, lhi * 4 + r, 64);
    l_o[r] = __shfl(l_s, lhi * 4 + r, 64);
  }

  // merge the two k-groups' partials (pool reused; K/V/P dead)
  f32x4* comb = (f32x4*)pool;
  const int ci = (rw * 64 + lane) * 6;
  if (g == 0) {
#pragma unroll
    for (int n = 0; n < 4; n++) comb[ci + n] = o[n];
    comb[ci + 4] = (f32x4){m_o[0], m_o[1], m_o[2], m_o[3]};
    comb[ci + 5] = (f32x4){l_o[0], l_o[1], l_o[2], l_o[3]};
  }
  __syncthreads();
  if (g == 1) {
    f32x4 m0 = comb[ci + 4];
    f32x4 l0 = comb[ci + 5];
    float a0[4], a1[4], inv[4];
#pragma unroll
    for (int r = 0; r < 4; r++) {
      const float m = fmaxf(m0[r], m_o[r]);
      a0[r] = __builtin_amdgcn_exp2f((m0[r] - m) * CEXP);
      a1[r] = __builtin_amdgcn_exp2f((m_o[r] - m) * CEXP);
      inv[r] = 1.0f / (l0[r] * a0[r] + l_o[r] * a1[r]);
    }
#pragma unroll
    for (int n = 0; n < 4; n++) {
      f32x4 o0 = comb[ci + n];
#pragma unroll
      for (int r = 0; r < 4; r++) {
        const int rowg = qt * 64 + rw * 16 + lhi * 4 + r;
        const float val = (o0[r] * a0[r] + o[n][r] * a1[r]) * inv[r];
        Aout[(((size_t)(b * SEQ + rowg)) << 10) + h * 64 + n * 16 + l15] = f2bf(val);
      }
    }
  }
}

// ---------------- out projection: f32 out = Ab @ Wo^T + bo -------------------
// 128x64 tile, BK=64, 2-phase dbuf, swizzled. grid (32,16) = 2/CU.
__global__ __launch_bounds__(256) void oproj_kernel(
    const u16* __restrict__ X, const u16* __restrict__ W,
    const float* __restrict__ bias, float* __restrict__ Out) {
  __shared__ u16 As[2][128 * 64];
  __shared__ u16 Bs[2][64 * 64];

  const int tid  = threadIdx.x;
  const int lane = tid & 63;
  const int wid  = tid >> 6;
  const int wm   = wid >> 1, wn = wid & 1;
  const int l15  = lane & 15;
  const int lhi  = lane >> 4;
  const int bm   = blockIdx.x * 128;
  const int bn   = blockIdx.y * 64;

  f32x4 acc[4][2];
#pragma unroll
  for (int i = 0; i < 4; i++)
#pragma unroll
    for (int j = 0; j < 2; j++) acc[i][j] = (f32x4){0.f, 0.f, 0.f, 0.f};

  const int lrow  = lane >> 3;
  const int gcol8 = lane & 7;

#define OPROJ_STAGE(buf, k0)                                                      \
  {                                                                               \
    _Pragma("unroll")                                                             \
    for (int c = 0; c < 4; c++) {                                                 \
      const int row  = c * 32 + wid * 8 + lrow;                                   \
      const int scol = (gcol8 ^ (row & 7)) * 8;                                   \
      gll16(X + (size_t)(bm + row) * HID + (k0) + scol,                           \
            (char*)&As[buf][0] + c * 4096 + wid * 1024);                          \
      if (c < 2)                                                                  \
        gll16(W + (size_t)(bn + row) * HID + (k0) + scol,                         \
              (char*)&Bs[buf][0] + c * 4096 + wid * 1024);                        \
    }                                                                             \
  }

  OPROJ_STAGE(0, 0);
  for (int t = 0; t < 16; t++) {
    __syncthreads();
    if (t < 15) OPROJ_STAGE((t + 1) & 1, (t + 1) * 64);
    const u16* A = &As[t & 1][0];
    const u16* B = &Bs[t & 1][0];
#pragma unroll
    for (int ks = 0; ks < 2; ks++) {
      bf16x8 af[4], bfm[2];
#pragma unroll
      for (int i = 0; i < 4; i++) {
        const int row = wm * 64 + i * 16 + l15;
        af[i] = *(const bf16x8*)&A[row * 64 + swz(row, ks * 32 + lhi * 8)];
      }
#pragma unroll
      for (int j = 0; j < 2; j++) {
        const int row = wn * 32 + j * 16 + l15;
        bfm[j] = *(const bf16x8*)&B[row * 64 + swz(row, ks * 32 + lhi * 8)];
      }
#pragma unroll
      for (int i = 0; i < 4; i++)
#pragma unroll
        for (int j = 0; j < 2; j++)
          acc[i][j] = __builtin_amdgcn_mfma_f32_16x16x32_bf16(af[i], bfm[j], acc[i][j], 0, 0, 0);
    }
  }
#undef OPROJ_STAGE

#pragma unroll
  for (int j = 0; j < 2; j++) {
    const int n = bn + wn * 32 + j * 16 + l15;
    const float bv_ = bias[n];
#pragma unroll
    for (int i = 0; i < 4; i++)
#pragma unroll
      for (int r = 0; r < 4; r++) {
        const int m = bm + wm * 64 + i * 16 + lhi * 4 + r;
        Out[(size_t)m * HID + n] = acc[i][j][r] + bv_;
      }
  }
}

// ---------------- launch ------------------------------------------------------
extern "C" void kernel_launch(void* const* d_in, const int* in_sizes, int n_in,
                              void* d_out, int out_size, void* d_ws, size_t ws_size,
                              hipStream_t stream) {
  const float* q  = (const float*)d_in[0];
  const float* k  = (const float*)d_in[1];
  const float* v  = (const float*)d_in[2];
  const float* Wq = (const float*)d_in[3];
  const float* bq = (const float*)d_in[4];
  const float* Wk = (const float*)d_in[5];
  const float* bk = (const float*)d_in[6];
  const float* Wv = (const float*)d_in[7];
  const float* bv = (const float*)d_in[8];
  const float* Wo = (const float*)d_in[9];
  const float* bo = (const float*)d_in[10];

  u16* ws   = (u16*)d_ws;
  u16* wqkv = ws;                     // Wq,Wk,Wv bf16 @ 0,1M,2M
  u16* wob  = ws + 3u * MEG;          // Wo bf16
  u16* qb   = ws + 4u * MEG;          // q bf16; reused as Ab after proj
  u16* Qb   = ws + 8u * MEG;          // [B,H,S,D]
  u16* Kb   = ws + 12u * MEG;         // [B,H,S,D]
  u16* Vtb  = ws + 16u * MEG;         // [B,H,D,S]
  u16* Ab   = qb;
  u16* kbf  = (u16*)d_out;            // k bf16 in d_out scratch
  u16* vbf  = (u16*)d_out + 4u * MEG; // v bf16

  cvt_kernel<<<dim3(1024, 16), 256, 0, stream>>>(Wq, Wk, Wv, Wo, q, k, v, ws, kbf);

  proj_kernel<<<dim3(32, 8, 3), 256, 0, stream>>>(qb, kbf, vbf, wqkv, bq, bk, bv,
                                                  Qb, Kb, Vtb);

  attn_kernel<<<dim3(1024), 512, 0, stream>>>(Qb, Kb, Vtb, Ab);

  oproj_kernel<<<dim3(32, 16), 256, 0, stream>>>(Ab, wob, bo, (float*)d_out);
}

// Round 7
// 117.102 us; speedup vs baseline: 2.7970x; 1.0217x over previous
//
#include <hip/hip_runtime.h>
#include <hip/hip_bf16.h>

// MHA forward, MI355X gfx950.
// cvt (weights+activations -> bf16) -> batched QKV proj GEMM (m97 single-buf,
// swizzled LDS, global_load_lds, 3 blocks/CU) -> causal flash attn (swapped-QK
// in-register softmax + T13 defer-max + T5 setprio, T14 reg-prefetch,
// XCD remap + LPT order) -> out GEMM (m97 single-buf).
// HIDDEN=1024, HEADS=16, HEAD_DIM=64, B=2, S=2048.

typedef __attribute__((ext_vector_type(4))) float f32x4;
typedef __attribute__((ext_vector_type(8))) short bf16x8;
typedef unsigned short u16;

#define SEQ   2048
#define NH    16
#define HD    64
#define HID   1024
#define CEXP  0.1803368801f  // 0.125 * log2(e)
#define MEG   1048576u

// HW round-to-nearest-even f32->bf16.
static __device__ __forceinline__ u16 f2bf(float f) {
  union { __hip_bfloat16 h; u16 u; } c;
  c.h = __float2bfloat16(f);
  return c.u;
}

// XOR swizzle on 8-elem bf16 chunks within a 64-elem row (T2, G4).
static __device__ __forceinline__ int swz(int row, int col8) {
  return col8 ^ ((row & 7) << 3);
}

// async global->LDS, 16B/lane; lds dest wave-uniform base (guide §5).
static __device__ __forceinline__ void gll16(const void* g, void* l) {
  __builtin_amdgcn_global_load_lds(
      (const __attribute__((address_space(1))) void*)g,
      (__attribute__((address_space(3))) void*)l, 16, 0, 0);
}

// ---------------- f32 -> bf16 conversion: 16 x 1M-elem slices ----------------
__global__ __launch_bounds__(256) void cvt_kernel(
    const float* __restrict__ Wq, const float* __restrict__ Wk,
    const float* __restrict__ Wv, const float* __restrict__ Wo,
    const float* __restrict__ q, const float* __restrict__ k,
    const float* __restrict__ v,
    u16* __restrict__ wsout, u16* __restrict__ dob) {
  const int y = blockIdx.y;
  const int c = y & 3;
  const float* src;
  u16* dst;
  if (y < 4) {
    src = (y == 0) ? Wq : (y == 1) ? Wk : (y == 2) ? Wv : Wo;
    dst = wsout + (size_t)y * MEG;
  } else if (y < 8) {
    src = q + (size_t)c * MEG;
    dst = wsout + 4u * MEG + (size_t)c * MEG;
  } else if (y < 12) {
    src = k + (size_t)c * MEG;
    dst = dob + (size_t)c * MEG;
  } else {
    src = v + (size_t)c * MEG;
    dst = dob + 4u * MEG + (size_t)c * MEG;
  }
  int i = (blockIdx.x * 256 + threadIdx.x) * 4;
  float4 f = *(const float4*)(src + i);
  ushort4 o;
  o.x = f2bf(f.x); o.y = f2bf(f.y); o.z = f2bf(f.z); o.w = f2bf(f.w);
  *(ushort4*)(dst + i) = o;
}

// -------- batched QKV projection: C = X @ W^T + b, scatter to heads ----------
// z=0: Q -> [B,H,S,D]; z=1: K -> [B,H,S,D]; z=2: V -> [B,H,D,S] (transposed).
// 128x128 tile, BK=64, m97 single-buffer gll staging (32 KB -> 3 blocks/CU).
__global__ __launch_bounds__(256) void proj_kernel(
    const u16* __restrict__ Xq, const u16* __restrict__ Xk,
    const u16* __restrict__ Xv, const u16* __restrict__ Wc,
    const float* __restrict__ bq, const float* __restrict__ bk,
    const float* __restrict__ bvp,
    u16* __restrict__ Qo, u16* __restrict__ Ko, u16* __restrict__ Vto) {
  __shared__ u16 As[128 * 64];
  __shared__ u16 Bs[128 * 64];

  const int tid  = threadIdx.x;
  const int lane = tid & 63;
  const int wid  = tid >> 6;
  const int wm   = wid >> 1, wn = wid & 1;
  const int l15  = lane & 15;
  const int lhi  = lane >> 4;
  const int z    = blockIdx.z;
  const int bm   = blockIdx.x * 128;
  const int bn   = blockIdx.y * 128;

  const u16* X = (z == 0) ? Xq : (z == 1) ? Xk : Xv;
  const u16* W = Wc + (size_t)z * (HID * HID);
  const float* bias = (z == 0) ? bq : (z == 1) ? bk : bvp;

  f32x4 acc[4][4];
#pragma unroll
  for (int i = 0; i < 4; i++)
#pragma unroll
    for (int j = 0; j < 4; j++) acc[i][j] = (f32x4){0.f, 0.f, 0.f, 0.f};

  const int lrow  = lane >> 3;      // 0..7
  const int gcol8 = lane & 7;       // 8-elem chunk index

  for (int t = 0; t < 16; t++) {
    const int k0 = t * 64;
#pragma unroll
    for (int c = 0; c < 4; c++) {
      const int row  = c * 32 + wid * 8 + lrow;
      const int scol = (gcol8 ^ (row & 7)) * 8;  // inverse-swizzled source
      gll16(X + (size_t)(bm + row) * HID + k0 + scol,
            (char*)As + c * 4096 + wid * 1024);
      gll16(W + (size_t)(bn + row) * HID + k0 + scol,
            (char*)Bs + c * 4096 + wid * 1024);
    }
    __syncthreads();  // drains gll vmcnt
#pragma unroll
    for (int ks = 0; ks < 2; ks++) {
      bf16x8 af[4], bfm[4];
#pragma unroll
      for (int i = 0; i < 4; i++) {
        const int row = wm * 64 + i * 16 + l15;
        af[i] = *(const bf16x8*)&As[row * 64 + swz(row, ks * 32 + lhi * 8)];
      }
#pragma unroll
      for (int j = 0; j < 4; j++) {
        const int row = wn * 64 + j * 16 + l15;
        bfm[j] = *(const bf16x8*)&Bs[row * 64 + swz(row, ks * 32 + lhi * 8)];
      }
#pragma unroll
      for (int i = 0; i < 4; i++)
#pragma unroll
        for (int j = 0; j < 4; j++)
          acc[i][j] = __builtin_amdgcn_mfma_f32_16x16x32_bf16(af[i], bfm[j], acc[i][j], 0, 0, 0);
    }
    __syncthreads();  // all reads done before next stage overwrites
  }

  // epilogue: bias + scatter to heads
  const int bb = bm >> 11;  // tile never crosses batch
#pragma unroll
  for (int j = 0; j < 4; j++) {
    const int n = bn + wn * 64 + j * 16 + l15;
    const float bv_ = bias[n];
    const int h = n >> 6, d = n & 63;
    if (z == 2) {
#pragma unroll
      for (int i = 0; i < 4; i++) {
        const int s0 = (bm + wm * 64 + i * 16 + lhi * 4) & 2047;
        ushort4 t;
        t.x = f2bf(acc[i][j][0] + bv_);
        t.y = f2bf(acc[i][j][1] + bv_);
        t.z = f2bf(acc[i][j][2] + bv_);
        t.w = f2bf(acc[i][j][3] + bv_);
        *(ushort4*)&Vto[((size_t)(bb * NH + h) * HD + d) * SEQ + s0] = t;
      }
    } else {
      u16* O = z ? Ko : Qo;
#pragma unroll
      for (int i = 0; i < 4; i++)
#pragma unroll
        for (int r = 0; r < 4; r++) {
          const int m = bm + wm * 64 + i * 16 + lhi * 4 + r;
          const int s = m & 2047;
          O[(((size_t)(bb * NH + h) * SEQ + s) << 6) + d] = f2bf(acc[i][j][r] + bv_);
        }
    }
  }
}

// ---------------- causal flash attention -------------------------------------
// Q,K: bf16 [B,H,S,D]; Vt: bf16 [B,H,D,S]; out: bf16 [B,S,H*D].
// 512 thr = 2 k-groups x 4 row-waves; swapped QK^T (lane = one q-row).
// T14 issue-early/write-late staging; T13 defer-max; T5 setprio.
__global__ __launch_bounds__(512) void attn_kernel(
    const u16* __restrict__ Q, const u16* __restrict__ K,
    const u16* __restrict__ Vt, u16* __restrict__ Aout) {
  // K[g] @ g*8192, V[g] @ 16384+g*8192 ([64][64] swizzled),
  // Psh[w] @ 32768+wid*2304 ([16][72]). total 51200 B -> 3 blocks/CU.
  __shared__ __align__(16) char pool[51200];

  const int tid  = threadIdx.x;
  const int lane = tid & 63;
  const int wid  = tid >> 6;
  const int rw   = wid & 3;
  const int g    = wid >> 2;
  const int l15  = lane & 15;
  const int lhi  = lane >> 4;

  // XCD-locality remap (T1) + LPT: longest q-tiles first.
  const int flat = blockIdx.x;
  const int slot = flat >> 3;
  const int bh   = (flat & 7) * 4 + (slot & 3);
  const int qt   = 31 - (slot >> 2);
  const int b    = bh >> 4, h = bh & 15;
  const size_t base = (size_t)bh * SEQ * HD;

  u16* Ksh = (u16*)(pool + g * 8192);
  u16* Vsh = (u16*)(pool + 16384 + g * 8192);
  u16* Psh = (u16*)(pool + 32768 + wid * 2304);

  const int qrow = qt * 64 + rw * 16 + l15;
  bf16x8 aq[2];
  aq[0] = *(const bf16x8*)&Q[base + (size_t)qrow * HD + lhi * 8];
  aq[1] = *(const bf16x8*)&Q[base + (size_t)qrow * HD + 32 + lhi * 8];

  f32x4 o[4];
#pragma unroll
  for (int n = 0; n < 4; n++) o[n] = (f32x4){0.f, 0.f, 0.f, 0.f};
  float m_s = -1e30f, l_s = 0.f;

  // staging mapping: 256 thr/group; row 0..63, 16-col chunk
  const int gt   = tid & 255;
  const int srow = gt >> 2;
  const int sd   = (gt & 3) * 16;

  bf16x8 pk0, pk1, pv0, pv1;  // prefetched next-tile K/V (T14)

#define ATTN_LOAD(kt_)                                                            \
  {                                                                               \
    const u16* kp = K + base + (size_t)((kt_) * 64 + srow) * HD + sd;             \
    pk0 = *(const bf16x8*)kp;                                                     \
    pk1 = *(const bf16x8*)(kp + 8);                                               \
    const u16* vp = Vt + base + (size_t)srow * SEQ + (kt_) * 64 + sd;             \
    pv0 = *(const bf16x8*)vp;                                                     \
    pv1 = *(const bf16x8*)(vp + 8);                                               \
  }

  if (g <= qt) ATTN_LOAD(g);

  const int nsteps = qt / 2 + 1;
  for (int it = 0; it < nsteps; ++it) {
    const int kt = 2 * it + g;
    const bool act = (kt <= qt);
    __syncthreads();  // prior tile's LDS reads done
    if (act) {        // write prefetched tile into LDS (swizzled both sides)
      *(bf16x8*)&Ksh[srow * 64 + swz(srow, sd)]     = pk0;
      *(bf16x8*)&Ksh[srow * 64 + swz(srow, sd + 8)] = pk1;
      *(bf16x8*)&Vsh[srow * 64 + swz(srow, sd)]     = pv0;
      *(bf16x8*)&Vsh[srow * 64 + swz(srow, sd + 8)] = pv1;
    }
    const int ktn = kt + 2;
    if (ktn <= qt) ATTN_LOAD(ktn);  // issue-early: lands during compute
    __syncthreads();  // LDS writes visible
    if (act) {
      // S^T = mfma(K, Q): lane l15 = q-row; regs hold k = kt*64 + n*16 + lhi*4 + r
      f32x4 sc[4];
      __builtin_amdgcn_s_setprio(1);
#pragma unroll
      for (int n = 0; n < 4; n++) {
        sc[n] = (f32x4){0.f, 0.f, 0.f, 0.f};
#pragma unroll
        for (int ks = 0; ks < 2; ks++) {
          const int krow = n * 16 + l15;
          bf16x8 bk = *(const bf16x8*)&Ksh[krow * 64 + swz(krow, ks * 32 + lhi * 8)];
          sc[n] = __builtin_amdgcn_mfma_f32_16x16x32_bf16(bk, aq[ks], sc[n], 0, 0, 0);
        }
      }
      __builtin_amdgcn_s_setprio(0);
      if (kt == qt) {  // causal mask on diagonal tile
#pragma unroll
        for (int n = 0; n < 4; n++)
#pragma unroll
          for (int r = 0; r < 4; r++)
            if (kt * 64 + n * 16 + lhi * 4 + r > qrow) sc[n][r] = -1e30f;
      }
      // ---- online softmax, defer-max (T13) ----
      float mx = -1e30f;
#pragma unroll
      for (int n = 0; n < 4; n++)
        mx = fmaxf(mx, fmaxf(fmaxf(sc[n][0], sc[n][1]), fmaxf(sc[n][2], sc[n][3])));
      mx = fmaxf(mx, __shfl_xor(mx, 16, 64));
      mx = fmaxf(mx, __shfl_xor(mx, 32, 64));
      if (__any(mx > m_s + 64.0f)) {  // raw-score THR (e^8 P-bound)
        const float mnew = fmaxf(m_s, mx);
        const float fac = __builtin_amdgcn_exp2f((m_s - mnew) * CEXP);
        l_s *= fac;
        m_s = mnew;
        float facr[4];
#pragma unroll
        for (int r = 0; r < 4; r++) facr[r] = __shfl(fac, lhi * 4 + r, 64);
#pragma unroll
        for (int n = 0; n < 4; n++) {
          o[n][0] *= facr[0]; o[n][1] *= facr[1];
          o[n][2] *= facr[2]; o[n][3] *= facr[3];
        }
      }
      const float nmc = -m_s * CEXP;
      float ps = 0.f;
      u16 pb[4][4];
#pragma unroll
      for (int n = 0; n < 4; n++)
#pragma unroll
        for (int r = 0; r < 4; r++) {
          const float e = __builtin_amdgcn_exp2f(fmaf(sc[n][r], CEXP, nmc));
          ps += e;
          pb[n][r] = f2bf(e);
        }
      ps += __shfl_xor(ps, 16, 64);
      ps += __shfl_xor(ps, 32, 64);
      l_s += ps;
      // P -> per-wave LDS -> A-frag
#pragma unroll
      for (int n = 0; n < 4; n++) {
        ushort4 t; t.x = pb[n][0]; t.y = pb[n][1]; t.z = pb[n][2]; t.w = pb[n][3];
        *(ushort4*)&Psh[l15 * 72 + n * 16 + lhi * 4] = t;
      }
      bf16x8 ap0 = *(const bf16x8*)&Psh[l15 * 72 + lhi * 8];
      bf16x8 ap1 = *(const bf16x8*)&Psh[l15 * 72 + 32 + lhi * 8];
      __builtin_amdgcn_s_setprio(1);
#pragma unroll
      for (int n = 0; n < 4; n++) {
        const int vrow = n * 16 + l15;
        bf16x8 bv0 = *(const bf16x8*)&Vsh[vrow * 64 + swz(vrow, lhi * 8)];
        bf16x8 bv1 = *(const bf16x8*)&Vsh[vrow * 64 + swz(vrow, 32 + lhi * 8)];
        o[n] = __builtin_amdgcn_mfma_f32_16x16x32_bf16(ap0, bv0, o[n], 0, 0, 0);
        o[n] = __builtin_amdgcn_mfma_f32_16x16x32_bf16(ap1, bv1, o[n], 0, 0, 0);
      }
      __builtin_amdgcn_s_setprio(0);
    }
  }
#undef ATTN_LOAD

  __syncthreads();
  float m_o[4], l_o[4];
#pragma unroll
  for (int r = 0; r < 4; r++) {
    m_o[r] = __shfl(m_s, lhi * 4 + r, 64);
    l_o[r] = __shfl(l_s, lhi * 4 + r, 64);
  }

  // merge the two k-groups' partials (pool reused; K/V/P dead)
  f32x4* comb = (f32x4*)pool;
  const int ci = (rw * 64 + lane) * 6;
  if (g == 0) {
#pragma unroll
    for (int n = 0; n < 4; n++) comb[ci + n] = o[n];
    comb[ci + 4] = (f32x4){m_o[0], m_o[1], m_o[2], m_o[3]};
    comb[ci + 5] = (f32x4){l_o[0], l_o[1], l_o[2], l_o[3]};
  }
  __syncthreads();
  if (g == 1) {
    f32x4 m0 = comb[ci + 4];
    f32x4 l0 = comb[ci + 5];
    float a0[4], a1[4], inv[4];
#pragma unroll
    for (int r = 0; r < 4; r++) {
      const float m = fmaxf(m0[r], m_o[r]);
      a0[r] = __builtin_amdgcn_exp2f((m0[r] - m) * CEXP);
      a1[r] = __builtin_amdgcn_exp2f((m_o[r] - m) * CEXP);
      inv[r] = 1.0f / (l0[r] * a0[r] + l_o[r] * a1[r]);
    }
#pragma unroll
    for (int n = 0; n < 4; n++) {
      f32x4 o0 = comb[ci + n];
#pragma unroll
      for (int r = 0; r < 4; r++) {
        const int rowg = qt * 64 + rw * 16 + lhi * 4 + r;
        const float val = (o0[r] * a0[r] + o[n][r] * a1[r]) * inv[r];
        Aout[(((size_t)(b * SEQ + rowg)) << 10) + h * 64 + n * 16 + l15] = f2bf(val);
      }
    }
  }
}

// ---------------- out projection: f32 out = Ab @ Wo^T + bo -------------------
// 128x64 tile, BK=64, m97 single-buffer (24 KB). grid (32,16).
__global__ __launch_bounds__(256) void oproj_kernel(
    const u16* __restrict__ X, const u16* __restrict__ W,
    const float* __restrict__ bias, float* __restrict__ Out) {
  __shared__ u16 As[128 * 64];
  __shared__ u16 Bs[64 * 64];

  const int tid  = threadIdx.x;
  const int lane = tid & 63;
  const int wid  = tid >> 6;
  const int wm   = wid >> 1, wn = wid & 1;
  const int l15  = lane & 15;
  const int lhi  = lane >> 4;
  const int bm   = blockIdx.x * 128;
  const int bn   = blockIdx.y * 64;

  f32x4 acc[4][2];
#pragma unroll
  for (int i = 0; i < 4; i++)
#pragma unroll
    for (int j = 0; j < 2; j++) acc[i][j] = (f32x4){0.f, 0.f, 0.f, 0.f};

  const int lrow  = lane >> 3;
  const int gcol8 = lane & 7;

  for (int t = 0; t < 16; t++) {
    const int k0 = t * 64;
#pragma unroll
    for (int c = 0; c < 4; c++) {
      const int row  = c * 32 + wid * 8 + lrow;
      const int scol = (gcol8 ^ (row & 7)) * 8;
      gll16(X + (size_t)(bm + row) * HID + k0 + scol,
            (char*)As + c * 4096 + wid * 1024);
      if (c < 2)
        gll16(W + (size_t)(bn + row) * HID + k0 + scol,
              (char*)Bs + c * 4096 + wid * 1024);
    }
    __syncthreads();
#pragma unroll
    for (int ks = 0; ks < 2; ks++) {
      bf16x8 af[4], bfm[2];
#pragma unroll
      for (int i = 0; i < 4; i++) {
        const int row = wm * 64 + i * 16 + l15;
        af[i] = *(const bf16x8*)&As[row * 64 + swz(row, ks * 32 + lhi * 8)];
      }
#pragma unroll
      for (int j = 0; j < 2; j++) {
        const int row = wn * 32 + j * 16 + l15;
        bfm[j] = *(const bf16x8*)&Bs[row * 64 + swz(row, ks * 32 + lhi * 8)];
      }
#pragma unroll
      for (int i = 0; i < 4; i++)
#pragma unroll
        for (int j = 0; j < 2; j++)
          acc[i][j] = __builtin_amdgcn_mfma_f32_16x16x32_bf16(af[i], bfm[j], acc[i][j], 0, 0, 0);
    }
    __syncthreads();
  }

#pragma unroll
  for (int j = 0; j < 2; j++) {
    const int n = bn + wn * 32 + j * 16 + l15;
    const float bv_ = bias[n];
#pragma unroll
    for (int i = 0; i < 4; i++)
#pragma unroll
      for (int r = 0; r < 4; r++) {
        const int m = bm + wm * 64 + i * 16 + lhi * 4 + r;
        Out[(size_t)m * HID + n] = acc[i][j][r] + bv_;
      }
  }
}

// ---------------- launch ------------------------------------------------------
extern "C" void kernel_launch(void* const* d_in, const int* in_sizes, int n_in,
                              void* d_out, int out_size, void* d_ws, size_t ws_size,
                              hipStream_t stream) {
  const float* q  = (const float*)d_in[0];
  const float* k  = (const float*)d_in[1];
  const float* v  = (const float*)d_in[2];
  const float* Wq = (const float*)d_in[3];
  const float* bq = (const float*)d_in[4];
  const float* Wk = (const float*)d_in[5];
  const float* bk = (const float*)d_in[6];
  const float* Wv = (const float*)d_in[7];
  const float* bv = (const float*)d_in[8];
  const float* Wo = (const float*)d_in[9];
  const float* bo = (const float*)d_in[10];

  u16* ws   = (u16*)d_ws;
  u16* wqkv = ws;                     // Wq,Wk,Wv bf16 @ 0,1M,2M
  u16* wob  = ws + 3u * MEG;          // Wo bf16
  u16* qb   = ws + 4u * MEG;          // q bf16; reused as Ab after proj
  u16* Qb   = ws + 8u * MEG;          // [B,H,S,D]
  u16* Kb   = ws + 12u * MEG;         // [B,H,S,D]
  u16* Vtb  = ws + 16u * MEG;         // [B,H,D,S]
  u16* Ab   = qb;
  u16* kbf  = (u16*)d_out;            // k bf16 in d_out scratch
  u16* vbf  = (u16*)d_out + 4u * MEG; // v bf16

  cvt_kernel<<<dim3(1024, 16), 256, 0, stream>>>(Wq, Wk, Wv, Wo, q, k, v, ws, kbf);

  proj_kernel<<<dim3(32, 8, 3), 256, 0, stream>>>(qb, kbf, vbf, wqkv, bq, bk, bv,
                                                  Qb, Kb, Vtb);

  attn_kernel<<<dim3(1024), 512, 0, stream>>>(Qb, Kb, Vtb, Ab);

  oproj_kernel<<<dim3(32, 16), 256, 0, stream>>>(Ab, wob, bo, (float*)d_out);
}